// Round 2
// baseline (30929.431 us; speedup 1.0000x reference)
//
#include <hip/hip_runtime.h>
#include <math.h>

#define Bz   256
#define Tz   512
#define Sz   8
#define CD1  5
#define Hz   520
#define H4   2080
#define Ez   1024
#define Dz   1040

__device__ __forceinline__ void fma4(float4& a, float h, const float4 v) {
    a.x += h * v.x; a.y += h * v.y; a.z += h * v.z; a.w += h * v.w;
}

// One-time repack: W_hh[k][gate*520+j] -> wt[k][j][gate] (float4-able),
// W_ih likewise, b_lstm -> bt[j][gate].
__global__ void k_prep(const float* __restrict__ whh, const float* __restrict__ wih,
                       const float* __restrict__ b,
                       float* __restrict__ wt, float* __restrict__ wih_t, float* __restrict__ bt) {
    int idx = blockIdx.x * 256 + threadIdx.x;
    const int total = (Hz + CD1 + 1) * H4;   // 526 * 2080
    if (idx >= total) return;
    int row = idx / H4, c = idx % H4;
    int j = c >> 2, g = c & 3;
    int src = g * Hz + j;
    if (row < Hz)            wt[idx] = whh[row * H4 + src];
    else if (row < Hz + CD1) wih_t[(row - Hz) * H4 + c] = wih[(row - Hz) * H4 + src];
    else                     bt[c] = b[src];
}

// out[m][n] = act( in[m][:] @ w[:][n] + bias[n] ), 8 rows per block (by), 256 threads over n.
template<int K, int N, int ACT>
__global__ void k_mlp(const float* __restrict__ in, const float* __restrict__ w,
                      const float* __restrict__ bias, float* __restrict__ out) {
    int n  = blockIdx.x * 256 + threadIdx.x;
    int m0 = blockIdx.y * 8;
    if (n >= N) return;
    float acc[8];
    float bv = bias[n];
    #pragma unroll
    for (int i = 0; i < 8; i++) acc[i] = bv;
    for (int k = 0; k < K; k++) {
        float wv = w[k * N + n];
        #pragma unroll
        for (int i = 0; i < 8; i++) acc[i] += in[(m0 + i) * K + k] * wv;
    }
    #pragma unroll
    for (int i = 0; i < 8; i++) {
        float v = acc[i];
        out[(m0 + i) * N + n] = ACT ? tanhf(v) : v;
    }
}

// Third encoder layer (linear) writing into h-stack [x | h0] with stride 520.
__global__ void k_enc3(const float* __restrict__ h2, const float* __restrict__ w,
                       const float* __restrict__ bias, const float* __restrict__ x,
                       float* __restrict__ hstack) {
    int n  = blockIdx.x * 256 + threadIdx.x;   // 0..511
    int m0 = blockIdx.y * 8;
    float acc[8];
    float bv = bias[n];
    #pragma unroll
    for (int i = 0; i < 8; i++) acc[i] = bv;
    for (int k = 0; k < Ez; k++) {
        float wv = w[k * 512 + n];
        #pragma unroll
        for (int i = 0; i < 8; i++) acc[i] += h2[(m0 + i) * Ez + k] * wv;
    }
    #pragma unroll
    for (int i = 0; i < 8; i++) hstack[(m0 + i) * Hz + Sz + n] = acc[i];
    if (blockIdx.x == 0 && threadIdx.x < Sz) {
        #pragma unroll
        for (int i = 0; i < 8; i++)
            hstack[(m0 + i) * Hz + threadIdx.x] = x[(m0 + i) * Sz + threadIdx.x];
    }
}

__device__ __forceinline__ float sigf(float v) { return 1.0f / (1.0f + expf(-v)); }

// One LSTM time step. Grid (17 j-tiles of 32, 16 row-tiles of 16).
// Thread handles (j, r) and (j, r+8): all 4 gates for each -> local elementwise update.
__global__ void k_step(const float* __restrict__ wt, const float* __restrict__ wih_t,
                       const float* __restrict__ bt, const float* __restrict__ rnn_in,
                       const float* __restrict__ deltas, const int* __restrict__ h_lens,
                       const float* __restrict__ hin, float* __restrict__ hout,
                       float* __restrict__ cbuf, float* __restrict__ last, int t) {
    int jl = threadIdx.x & 31, rl = threadIdx.x >> 5;
    int j  = blockIdx.x * 32 + jl;
    int r0 = blockIdx.y * 16;
    int ra = r0 + rl, rb = r0 + 8 + rl;
    int hla = h_lens[ra], hlb = h_lens[rb];
    bool acta = (t < hla), actb = (t < hlb);
    if (j >= Hz) return;
    if (!acta && !actb) return;

    const float4* bt4  = (const float4*)bt;
    const float4* wih4 = (const float4*)wih_t;
    const float4* wt4  = (const float4*)wt;

    float4 acc0 = bt4[j];
    float4 acc1 = acc0;

    #pragma unroll
    for (int q = 0; q < CD1; q++) {
        float4 wv = wih4[q * Hz + j];
        float u0 = rnn_in[(ra * Tz + t) * CD1 + q];
        float u1 = rnn_in[(rb * Tz + t) * CD1 + q];
        fma4(acc0, u0, wv);
        fma4(acc1, u1, wv);
    }

    const float4* h0p = (const float4*)(hin + (size_t)ra * Hz);
    const float4* h1p = (const float4*)(hin + (size_t)rb * Hz);
    #pragma unroll 2
    for (int kb = 0; kb < Hz / 4; kb++) {
        float4 ha = h0p[kb];
        float4 hb = h1p[kb];
        float4 w0 = wt4[(4 * kb + 0) * Hz + j];
        fma4(acc0, ha.x, w0); fma4(acc1, hb.x, w0);
        float4 w1 = wt4[(4 * kb + 1) * Hz + j];
        fma4(acc0, ha.y, w1); fma4(acc1, hb.y, w1);
        float4 w2 = wt4[(4 * kb + 2) * Hz + j];
        fma4(acc0, ha.z, w2); fma4(acc1, hb.z, w2);
        float4 w3 = wt4[(4 * kb + 3) * Hz + j];
        fma4(acc0, ha.w, w3); fma4(acc1, hb.w, w3);
    }

    if (acta) {
        float cp = cbuf[(size_t)ra * Hz + j];
        float ig = sigf(acc0.x), fg = sigf(acc0.y), gg = tanhf(acc0.z), og = sigf(acc0.w);
        float cn = fg * cp + ig * gg;
        float hn = og * tanhf(cn);
        cbuf[(size_t)ra * Hz + j] = cn;
        hout[(size_t)ra * Hz + j] = hn;
        if (t == hla - 1) {
            float d = deltas[ra * Tz + t];
            last[(size_t)ra * Hz + j] = (1.0f - d) * hin[(size_t)ra * Hz + j] + d * hn;
        }
    }
    if (actb) {
        float cp = cbuf[(size_t)rb * Hz + j];
        float ig = sigf(acc1.x), fg = sigf(acc1.y), gg = tanhf(acc1.z), og = sigf(acc1.w);
        float cn = fg * cp + ig * gg;
        float hn = og * tanhf(cn);
        cbuf[(size_t)rb * Hz + j] = cn;
        hout[(size_t)rb * Hz + j] = hn;
        if (t == hlb - 1) {
            float d = deltas[rb * Tz + t];
            last[(size_t)rb * Hz + j] = (1.0f - d) * hin[(size_t)rb * Hz + j] + d * hn;
        }
    }
}

// Final projection: (256,1040) @ (1040,8) + bias, one block per row.
__global__ void k_dec3(const float* __restrict__ z2, const float* __restrict__ w,
                       const float* __restrict__ bias, float* __restrict__ out) {
    int m = blockIdx.x, tid = threadIdx.x;
    float p[8];
    #pragma unroll
    for (int n = 0; n < 8; n++) p[n] = 0.0f;
    for (int k = tid; k < Dz; k += 256) {
        float zv = z2[(size_t)m * Dz + k];
        #pragma unroll
        for (int n = 0; n < 8; n++) p[n] += zv * w[k * 8 + n];
    }
    __shared__ float red[256][8];
    #pragma unroll
    for (int n = 0; n < 8; n++) red[tid][n] = p[n];
    __syncthreads();
    for (int s = 128; s > 0; s >>= 1) {
        if (tid < s) {
            #pragma unroll
            for (int n = 0; n < 8; n++) red[tid][n] += red[tid + s][n];
        }
        __syncthreads();
    }
    if (tid < 8) out[m * 8 + tid] = red[0][tid] + bias[tid];
}

extern "C" void kernel_launch(void* const* d_in, const int* in_sizes, int n_in,
                              void* d_out, int out_size, void* d_ws, size_t ws_size,
                              hipStream_t stream) {
    const float* x       = (const float*)d_in[0];
    const float* rnn_inp = (const float*)d_in[1];
    const float* deltas  = (const float*)d_in[2];
    const int*   h_lens  = (const int*)  d_in[3];
    const float* enc_w1  = (const float*)d_in[4];
    const float* enc_b1  = (const float*)d_in[5];
    const float* enc_w2  = (const float*)d_in[6];
    const float* enc_b2  = (const float*)d_in[7];
    const float* enc_w3  = (const float*)d_in[8];
    const float* enc_b3  = (const float*)d_in[9];
    const float* W_ih    = (const float*)d_in[10];
    const float* W_hh    = (const float*)d_in[11];
    const float* b_lstm  = (const float*)d_in[12];
    const float* dec_w1  = (const float*)d_in[13];
    const float* dec_b1  = (const float*)d_in[14];
    const float* dec_w2  = (const float*)d_in[15];
    const float* dec_b2  = (const float*)d_in[16];
    const float* dec_w3  = (const float*)d_in[17];
    const float* dec_b3  = (const float*)d_in[18];
    (void)in_sizes; (void)n_in; (void)out_size; (void)ws_size;

    float* ws    = (float*)d_ws;
    float* wt    = ws;  ws += Hz * H4;        // 1,081,600
    float* wih_t = ws;  ws += CD1 * H4;       // 10,400
    float* bt    = ws;  ws += H4;             // 2,080
    float* h1    = ws;  ws += Bz * Ez;        // 262,144
    float* h2    = ws;  ws += Bz * Ez;        // 262,144
    float* hA    = ws;  ws += Bz * Hz;        // 133,120
    float* hB    = ws;  ws += Bz * Hz;        // 133,120
    float* cbuf  = ws;  ws += Bz * Hz;        // 133,120
    float* last  = ws;  ws += Bz * Hz;        // 133,120
    float* z1    = ws;  ws += Bz * Dz;        // 266,240
    float* z2    = ws;  ws += Bz * Dz;        // 266,240
    float* outp  = (float*)d_out;

    hipMemsetAsync(cbuf, 0, (size_t)Bz * Hz * sizeof(float), stream);

    {
        int total = (Hz + CD1 + 1) * H4;
        k_prep<<<(total + 255) / 256, 256, 0, stream>>>(W_hh, W_ih, b_lstm, wt, wih_t, bt);
    }

    k_mlp<Sz, Ez, 1><<<dim3(4, 32), 256, 0, stream>>>(x,  enc_w1, enc_b1, h1);
    k_mlp<Ez, Ez, 1><<<dim3(4, 32), 256, 0, stream>>>(h1, enc_w2, enc_b2, h2);
    k_enc3<<<dim3(2, 32), 256, 0, stream>>>(h2, enc_w3, enc_b3, x, hA);

    for (int t = 0; t < Tz; t++) {
        const float* hin = (t & 1) ? hB : hA;
        float*       hou = (t & 1) ? hA : hB;
        k_step<<<dim3(17, 16), 256, 0, stream>>>(wt, wih_t, bt, rnn_inp, deltas, h_lens,
                                                 hin, hou, cbuf, last, t);
    }

    k_mlp<Hz, Dz, 1><<<dim3(5, 32), 256, 0, stream>>>(last, dec_w1, dec_b1, z1);
    k_mlp<Dz, Dz, 1><<<dim3(5, 32), 256, 0, stream>>>(z1,   dec_w2, dec_b2, z2);
    k_dec3<<<Bz, 256, 0, stream>>>(z2, dec_w3, dec_b3, outp);
}

// Round 3
// 16443.030 us; speedup vs baseline: 1.8810x; 1.8810x over previous
//
#include <hip/hip_runtime.h>
#include <math.h>

#define Bz   256
#define Tz   512
#define Sz   8
#define CD1  5
#define Hz   520
#define H4   2080
#define Ez   1024
#define Dz   1040

// persistent LSTM geometry
#define NG   16     // row groups
#define NSL  16     // j-slices per group (NG*NSL = 256 WGs, 1 per CU)
#define RG   16     // rows per group
#define JW   33     // j per slice (16*33 = 528 >= 520)
#define NW   132    // gate columns per slice (JW*4)
#define KW   520    // K extent
#define KD   260    // dwords per K row (KW/2)
#define NT   9      // n-tiles of 16 per slice (ceil(132/16))
#define KIT  17     // k-iterations of 32 (ceil(520/32))

typedef float f32x4 __attribute__((ext_vector_type(4)));
typedef short s16x8 __attribute__((ext_vector_type(8)));

__device__ __forceinline__ ushort f2bf(float f) {
    uint u = __float_as_uint(f);
    uint r = (u + 0x7fffu + ((u >> 16) & 1u)) >> 16;
    return (ushort)r;
}
__device__ __forceinline__ float bf2f(ushort h) { return __uint_as_float(((uint)h) << 16); }
__device__ __forceinline__ float sigf(float v) { return 1.0f / (1.0f + expf(-v)); }

// rank-sort rows by h_len descending (ties by index) — O(n^2), one block
__global__ void k_sort(const int* __restrict__ hl, int* __restrict__ sortedidx) {
    __shared__ int s[Bz];
    int i = threadIdx.x;
    s[i] = hl[i];
    __syncthreads();
    int mine = s[i], rank = 0;
    for (int j = 0; j < Bz; j++) {
        int o = s[j];
        rank += (o > mine) || (o == mine && j < i);
    }
    sortedidx[rank] = i;
}

// W_hh -> bf16, layout wbt[n][k], n = j*4+gate (2112 rows incl. zero pad), k = 0..519
__global__ void k_prep_w(const float* __restrict__ whh, ushort* __restrict__ wbt) {
    int idx = blockIdx.x * 256 + threadIdx.x;
    if (idx >= NW * NSL * KW) return;
    int n = idx / KW, k = idx - n * KW;
    int j = n >> 2, gate = n & 3;
    float v = (j < Hz) ? whh[(size_t)k * H4 + gate * Hz + j] : 0.0f;
    wbt[idx] = f2bf(v);
}

// permute h0_stack rows into sorted order: h_global[rank][k] = hA[sorted[rank]][k]
__global__ void k_hinit(const float* __restrict__ hA, const int* __restrict__ sortedidx,
                        float* __restrict__ h_global) {
    int idx = blockIdx.x * 256 + threadIdx.x;
    if (idx >= Bz * KW) return;
    int rank = idx / KW, k = idx - rank * KW;
    h_global[idx] = hA[(size_t)sortedidx[rank] * KW + k];
}

// out[m][n] = act( in[m][:] @ w[:][n] + bias[n] ), 4 rows/block, 256 threads over n
template<int K, int N, int ACT>
__global__ void k_mlp(const float* __restrict__ in, const float* __restrict__ w,
                      const float* __restrict__ bias, float* __restrict__ out) {
    int n  = blockIdx.x * 256 + threadIdx.x;
    int m0 = blockIdx.y * 4;
    if (n >= N) return;
    float acc[4];
    float bv = bias[n];
    #pragma unroll
    for (int i = 0; i < 4; i++) acc[i] = bv;
    for (int k = 0; k < K; k++) {
        float wv = w[k * N + n];
        #pragma unroll
        for (int i = 0; i < 4; i++) acc[i] += in[(m0 + i) * K + k] * wv;
    }
    #pragma unroll
    for (int i = 0; i < 4; i++) {
        float v = acc[i];
        out[(m0 + i) * N + n] = ACT ? tanhf(v) : v;
    }
}

// third encoder layer -> h-stack [x | h0], stride 520
__global__ void k_enc3(const float* __restrict__ h2, const float* __restrict__ w,
                       const float* __restrict__ bias, const float* __restrict__ x,
                       float* __restrict__ hstack) {
    int n  = blockIdx.x * 256 + threadIdx.x;   // 0..511
    int m0 = blockIdx.y * 4;
    float acc[4];
    float bv = bias[n];
    #pragma unroll
    for (int i = 0; i < 4; i++) acc[i] = bv;
    for (int k = 0; k < Ez; k++) {
        float wv = w[k * 512 + n];
        #pragma unroll
        for (int i = 0; i < 4; i++) acc[i] += h2[(m0 + i) * Ez + k] * wv;
    }
    #pragma unroll
    for (int i = 0; i < 4; i++) hstack[(m0 + i) * Hz + Sz + n] = acc[i];
    if (blockIdx.x == 0 && threadIdx.x < Sz) {
        #pragma unroll
        for (int i = 0; i < 4; i++)
            hstack[(m0 + i) * Hz + threadIdx.x] = x[(m0 + i) * Sz + threadIdx.x];
    }
}

// Persistent cooperative LSTM: 256 WGs (16 groups x 16 slices), weights resident in LDS.
__global__ __launch_bounds__(256, 1) void k_lstm(
        const ushort* __restrict__ wbt, const float* __restrict__ rnn_in,
        const float* __restrict__ deltas, const int* __restrict__ h_lens,
        const float* __restrict__ W_ih, const float* __restrict__ b_lstm,
        float* h_global, const int* __restrict__ sortedidx,
        float* __restrict__ last, unsigned int* bar) {
    __shared__ __align__(16) ushort w_lds[NW * KW];   // 137,280 B
    __shared__ __align__(16) ushort a_lds[RG * KW];   // 16,640 B (aliased as gates fp32[16][132])
    __shared__ float c_lds[RG * JW];                  // 2,112 B
    __shared__ int   rowg[RG];
    __shared__ int   hl_s[RG];

    const int tid = threadIdx.x;
    const int g   = blockIdx.x >> 4;
    const int s   = blockIdx.x & 15;

    if (tid < RG) {
        int o = sortedidx[g * RG + tid];
        rowg[tid] = o;
        hl_s[tid] = h_lens[o];
    }
    {   // stage weight slice: contiguous 132*260 dwords
        const uint* src = (const uint*)wbt + (size_t)s * NW * KD;
        uint* dst = (uint*)w_lds;
        for (int idx = tid; idx < NW * KD; idx += 256) dst[idx] = src[idx];
    }
    for (int idx = tid; idx < RG * JW; idx += 256) c_lds[idx] = 0.0f;
    __syncthreads();

    const int lane = tid & 63, wv = tid >> 6;
    const int l15 = lane & 15, quad = lane >> 4;
    const int ntile = (wv == 0) ? 3 : 2;
    int tiles[3] = { wv, wv + 4, wv + 8 };

    // W_ih / bias columns for this lane's n positions, held in registers
    float wihreg[3][CD1], breg[3];
    #pragma unroll
    for (int i = 0; i < 3; i++) {
        int nl = tiles[i] * 16 + l15;
        int jg = s * JW + (nl >> 2);
        bool ok = (i < ntile) && (nl < NW) && (jg < Hz);
        int col = (nl & 3) * Hz + jg;
        breg[i] = ok ? b_lstm[col] : 0.0f;
        #pragma unroll
        for (int q = 0; q < CD1; q++) wihreg[i][q] = ok ? W_ih[q * H4 + col] : 0.0f;
    }

    const int gmax = hl_s[0];
    volatile float* hg = h_global + (size_t)g * RG * KW;
    unsigned int myphase = 0;
    unsigned int* cnt = bar + g;
    unsigned int* ph  = bar + NG + g;

    for (int t = 0; t < gmax; t++) {
        if (t > 0) {   // group barrier: h(t-1) from the 16 slice-WGs visible (L3, volatile path)
            __syncthreads();
            if (tid == 0) {
                unsigned int old = __hip_atomic_fetch_add(cnt, 1u, __ATOMIC_RELEASE, __HIP_MEMORY_SCOPE_AGENT);
                if (old == NSL - 1) {
                    __hip_atomic_store(cnt, 0u, __ATOMIC_RELAXED, __HIP_MEMORY_SCOPE_AGENT);
                    __hip_atomic_fetch_add(ph, 1u, __ATOMIC_RELEASE, __HIP_MEMORY_SCOPE_AGENT);
                } else {
                    while (__hip_atomic_load(ph, __ATOMIC_ACQUIRE, __HIP_MEMORY_SCOPE_AGENT) == myphase)
                        __builtin_amdgcn_s_sleep(8);
                }
            }
            myphase++;
            __syncthreads();
        }

        // acc init = u_t @ W_ih + b  (VALU; keeps u out of the MFMA A so no extra barrier)
        float uu[4][CD1];
        #pragma unroll
        for (int r = 0; r < 4; r++) {
            const float* up = rnn_in + ((size_t)rowg[quad * 4 + r] * Tz + t) * CD1;
            #pragma unroll
            for (int q = 0; q < CD1; q++) uu[r][q] = up[q];
        }
        f32x4 acc[3];
        #pragma unroll
        for (int i = 0; i < 3; i++) {
            #pragma unroll
            for (int r = 0; r < 4; r++) {
                float a0 = breg[i];
                #pragma unroll
                for (int q = 0; q < CD1; q++) a0 += uu[r][q] * wihreg[i][q];
                acc[i][r] = a0;
            }
        }

        // read group h (fp32, coherent) once into registers
        float vreg[33];
        #pragma unroll
        for (int it = 0; it < 33; it++) {
            int idx = tid + it * 256;
            vreg[it] = (idx < RG * KW) ? hg[idx] : 0.0f;
        }

        // two MFMA passes: A = bf16_hi(h) then bf16_lo(h)  (weight-only bf16 error)
        #pragma unroll 1
        for (int pass = 0; pass < 2; pass++) {
            #pragma unroll
            for (int it = 0; it < 33; it++) {
                int idx = tid + it * 256;
                if (idx < RG * KW) {
                    float v = vreg[it];
                    ushort hi = f2bf(v);
                    a_lds[idx] = pass ? f2bf(v - bf2f(hi)) : hi;
                }
            }
            __syncthreads();
            for (int kit = 0; kit < KIT; kit++) {
                int kq = kit * 32 + quad * 8;
                s16x8 af = {0, 0, 0, 0, 0, 0, 0, 0};
                if (kq < KW)
                    af = __builtin_bit_cast(s16x8,
                        *(const uint4*)((const uint*)a_lds + l15 * KD + kit * 16 + quad * 4));
                #pragma unroll
                for (int i = 0; i < 3; i++) {
                    if (i >= ntile) break;
                    int nl = tiles[i] * 16 + l15;
                    s16x8 bf = {0, 0, 0, 0, 0, 0, 0, 0};
                    if (nl < NW && kq < KW)
                        bf = __builtin_bit_cast(s16x8,
                            *(const uint4*)((const uint*)w_lds + nl * KD + kit * 16 + quad * 4));
                    acc[i] = __builtin_amdgcn_mfma_f32_16x16x32_bf16(af, bf, acc[i], 0, 0, 0);
                }
            }
            __syncthreads();
        }

        // gates (pre-activation) -> LDS, aliasing a_lds
        float* gates = (float*)a_lds;
        #pragma unroll
        for (int i = 0; i < 3; i++) {
            if (i >= ntile) break;
            int nl = tiles[i] * 16 + l15;
            if (nl < NW) {
                #pragma unroll
                for (int r = 0; r < 4; r++) gates[(quad * 4 + r) * NW + nl] = acc[i][r];
            }
        }
        __syncthreads();

        // elementwise cell update; h store coherent; capture 'last' at t == hl-1
        for (int p = tid; p < RG * JW; p += 256) {
            int m = p / JW, jj = p - m * JW;
            int jglob = s * JW + jj;
            if (jglob < Hz && t < hl_s[m]) {
                float4 gv = *(const float4*)(gates + m * NW + jj * 4);
                float ig = sigf(gv.x), fg = sigf(gv.y), gt = tanhf(gv.z), og = sigf(gv.w);
                float cp = c_lds[p];
                float cn = fg * cp + ig * gt;
                float hn = og * tanhf(cn);
                c_lds[p] = cn;
                int hidx = m * KW + jglob;
                float hp = hg[hidx];
                hg[hidx] = hn;
                if (t == hl_s[m] - 1) {
                    int orig = rowg[m];
                    float d = deltas[(size_t)orig * Tz + t];
                    last[(size_t)orig * Hz + jglob] = (1.0f - d) * hp + d * hn;
                }
            }
        }
        __threadfence();   // drain h stores to coherence point before next barrier arrive
    }
}

// final projection: (256,1040) @ (1040,8) + bias, one block per row
__global__ void k_dec3(const float* __restrict__ z2, const float* __restrict__ w,
                       const float* __restrict__ bias, float* __restrict__ out) {
    int m = blockIdx.x, tid = threadIdx.x;
    float p[8];
    #pragma unroll
    for (int n = 0; n < 8; n++) p[n] = 0.0f;
    for (int k = tid; k < Dz; k += 256) {
        float zv = z2[(size_t)m * Dz + k];
        #pragma unroll
        for (int n = 0; n < 8; n++) p[n] += zv * w[k * 8 + n];
    }
    __shared__ float red[256][8];
    #pragma unroll
    for (int n = 0; n < 8; n++) red[tid][n] = p[n];
    __syncthreads();
    for (int s2 = 128; s2 > 0; s2 >>= 1) {
        if (tid < s2) {
            #pragma unroll
            for (int n = 0; n < 8; n++) red[tid][n] += red[tid + s2][n];
        }
        __syncthreads();
    }
    if (tid < 8) out[m * 8 + tid] = red[0][tid] + bias[tid];
}

extern "C" void kernel_launch(void* const* d_in, const int* in_sizes, int n_in,
                              void* d_out, int out_size, void* d_ws, size_t ws_size,
                              hipStream_t stream) {
    const float* x       = (const float*)d_in[0];
    const float* rnn_inp = (const float*)d_in[1];
    const float* deltas  = (const float*)d_in[2];
    const int*   h_lens  = (const int*)  d_in[3];
    const float* enc_w1  = (const float*)d_in[4];
    const float* enc_b1  = (const float*)d_in[5];
    const float* enc_w2  = (const float*)d_in[6];
    const float* enc_b2  = (const float*)d_in[7];
    const float* enc_w3  = (const float*)d_in[8];
    const float* enc_b3  = (const float*)d_in[9];
    const float* W_ih    = (const float*)d_in[10];
    const float* W_hh    = (const float*)d_in[11];
    const float* b_lstm  = (const float*)d_in[12];
    const float* dec_w1  = (const float*)d_in[13];
    const float* dec_b1  = (const float*)d_in[14];
    const float* dec_w2  = (const float*)d_in[15];
    const float* dec_b2  = (const float*)d_in[16];
    const float* dec_w3  = (const float*)d_in[17];
    const float* dec_b3  = (const float*)d_in[18];
    (void)in_sizes; (void)n_in; (void)out_size; (void)ws_size;

    char* base = (char*)d_ws;
    size_t off = 0;
    auto alloc = [&](size_t bytes) { void* p = base + off; off = (off + bytes + 255) & ~(size_t)255; return p; };
    ushort* wbt      = (ushort*)alloc((size_t)NW * NSL * KW * 2);   // 2,196,480
    float*  h_glob   = (float*) alloc((size_t)Bz * KW * 4);         // 532,480
    float*  hA       = (float*) alloc((size_t)Bz * KW * 4);
    float*  h1       = (float*) alloc((size_t)Bz * Ez * 4);
    float*  h2       = (float*) alloc((size_t)Bz * Ez * 4);
    float*  lastb    = (float*) alloc((size_t)Bz * Hz * 4);
    float*  z1       = (float*) alloc((size_t)Bz * Dz * 4);
    float*  z2       = (float*) alloc((size_t)Bz * Dz * 4);
    int*    sortedix = (int*)   alloc(Bz * 4);
    unsigned int* bar = (unsigned int*)alloc(2 * NG * 4);
    float*  outp = (float*)d_out;

    hipMemsetAsync(bar, 0, 2 * NG * 4, stream);
    k_sort<<<1, 256, 0, stream>>>(h_lens, sortedix);
    {
        int total = NW * NSL * KW;
        k_prep_w<<<(total + 255) / 256, 256, 0, stream>>>(W_hh, wbt);
    }

    k_mlp<Sz, Ez, 1><<<dim3(4, 64), 256, 0, stream>>>(x,  enc_w1, enc_b1, h1);
    k_mlp<Ez, Ez, 1><<<dim3(4, 64), 256, 0, stream>>>(h1, enc_w2, enc_b2, h2);
    k_enc3<<<dim3(2, 64), 256, 0, stream>>>(h2, enc_w3, enc_b3, x, hA);
    {
        int total = Bz * KW;
        k_hinit<<<(total + 255) / 256, 256, 0, stream>>>(hA, sortedix, h_glob);
    }

    {
        void* args[] = { (void*)&wbt, (void*)&rnn_inp, (void*)&deltas, (void*)&h_lens,
                         (void*)&W_ih, (void*)&b_lstm, (void*)&h_glob, (void*)&sortedix,
                         (void*)&lastb, (void*)&bar };
        hipLaunchCooperativeKernel(reinterpret_cast<void*>(k_lstm), dim3(NG * NSL), dim3(256),
                                   args, 0, stream);
    }

    k_mlp<Hz, Dz, 1><<<dim3(5, 64), 256, 0, stream>>>(lastb, dec_w1, dec_b1, z1);
    k_mlp<Dz, Dz, 1><<<dim3(5, 64), 256, 0, stream>>>(z1,   dec_w2, dec_b2, z2);
    k_dec3<<<Bz, 256, 0, stream>>>(z2, dec_w3, dec_b3, outp);
}

// Round 4
// 7696.312 us; speedup vs baseline: 4.0187x; 2.1365x over previous
//
#include <hip/hip_runtime.h>
#include <math.h>

#define Bz   256
#define Tz   512
#define Sz   8
#define CD1  5
#define Hz   520
#define H4   2080
#define Ez   1024
#define Dz   1040

// persistent LSTM geometry
#define NG   16     // row groups
#define NSL  16     // j-slices per group (NG*NSL = 256 WGs, 1 per CU)
#define RG   16     // rows per group
#define JW   33     // j per slice (16*33 = 528 >= 520)
#define NW   132    // gate columns per slice (JW*4)
#define KW   520    // K extent
#define KD   260    // dwords per K row (KW/2)
#define KIT  17     // k-iterations of 32 (ceil(520/32))
#define BARSTRIDE 32  // uints; 128B per barrier var to avoid line ping-pong

typedef float f32x4 __attribute__((ext_vector_type(4)));
typedef short s16x8 __attribute__((ext_vector_type(8)));

__device__ __forceinline__ ushort f2bf(float f) {
    uint u = __float_as_uint(f);
    uint r = (u + 0x7fffu + ((u >> 16) & 1u)) >> 16;
    return (ushort)r;
}
__device__ __forceinline__ float bf2f(ushort h) { return __uint_as_float(((uint)h) << 16); }
__device__ __forceinline__ float sigf(float v) { return 1.0f / (1.0f + expf(-v)); }

// rank-sort rows by h_len descending (ties by index) — O(n^2), one block
__global__ void k_sort(const int* __restrict__ hl, int* __restrict__ sortedidx) {
    __shared__ int s[Bz];
    int i = threadIdx.x;
    s[i] = hl[i];
    __syncthreads();
    int mine = s[i], rank = 0;
    for (int j = 0; j < Bz; j++) {
        int o = s[j];
        rank += (o > mine) || (o == mine && j < i);
    }
    sortedidx[rank] = i;
}

// W_hh -> bf16, layout wbt[n][k], n = j*4+gate (2112 rows incl. zero pad), k = 0..519
__global__ void k_prep_w(const float* __restrict__ whh, ushort* __restrict__ wbt) {
    int idx = blockIdx.x * 256 + threadIdx.x;
    if (idx >= NW * NSL * KW) return;
    int n = idx / KW, k = idx - n * KW;
    int j = n >> 2, gate = n & 3;
    float v = (j < Hz) ? whh[(size_t)k * H4 + gate * Hz + j] : 0.0f;
    wbt[idx] = f2bf(v);
}

// permute h0_stack rows into sorted order, packing fp32 -> (bf16_hi | bf16_lo<<16)
__global__ void k_hinit(const float* __restrict__ hA, const int* __restrict__ sortedidx,
                        uint* __restrict__ h_global) {
    int idx = blockIdx.x * 256 + threadIdx.x;
    if (idx >= Bz * KW) return;
    int rank = idx / KW, k = idx - rank * KW;
    float v = hA[(size_t)sortedidx[rank] * KW + k];
    ushort hi = f2bf(v);
    ushort lo = f2bf(v - bf2f(hi));
    h_global[idx] = (uint)hi | ((uint)lo << 16);
}

// out[m][n] = act( in[m][:] @ w[:][n] + bias[n] ), 4 rows/block, 256 threads over n
template<int K, int N, int ACT>
__global__ void k_mlp(const float* __restrict__ in, const float* __restrict__ w,
                      const float* __restrict__ bias, float* __restrict__ out) {
    int n  = blockIdx.x * 256 + threadIdx.x;
    int m0 = blockIdx.y * 4;
    if (n >= N) return;
    float acc[4];
    float bv = bias[n];
    #pragma unroll
    for (int i = 0; i < 4; i++) acc[i] = bv;
    for (int k = 0; k < K; k++) {
        float wv = w[k * N + n];
        #pragma unroll
        for (int i = 0; i < 4; i++) acc[i] += in[(m0 + i) * K + k] * wv;
    }
    #pragma unroll
    for (int i = 0; i < 4; i++) {
        float v = acc[i];
        out[(m0 + i) * N + n] = ACT ? tanhf(v) : v;
    }
}

// third encoder layer -> h-stack [x | h0], stride 520
__global__ void k_enc3(const float* __restrict__ h2, const float* __restrict__ w,
                       const float* __restrict__ bias, const float* __restrict__ x,
                       float* __restrict__ hstack) {
    int n  = blockIdx.x * 256 + threadIdx.x;   // 0..511
    int m0 = blockIdx.y * 4;
    float acc[4];
    float bv = bias[n];
    #pragma unroll
    for (int i = 0; i < 4; i++) acc[i] = bv;
    for (int k = 0; k < Ez; k++) {
        float wv = w[k * 512 + n];
        #pragma unroll
        for (int i = 0; i < 4; i++) acc[i] += h2[(m0 + i) * Ez + k] * wv;
    }
    #pragma unroll
    for (int i = 0; i < 4; i++) hstack[(m0 + i) * Hz + Sz + n] = acc[i];
    if (blockIdx.x == 0 && threadIdx.x < Sz) {
        #pragma unroll
        for (int i = 0; i < 4; i++)
            hstack[(m0 + i) * Hz + threadIdx.x] = x[(m0 + i) * Sz + threadIdx.x];
    }
}

// Persistent cooperative LSTM: 256 WGs (16 groups x 16 slices), weights resident in LDS.
// h exchanged as packed bf16 hi/lo via RELAXED agent-scope atomics (pipelined, cache-bypassing);
// ordering comes only from the per-group ACQ_REL/RELEASE/ACQUIRE barrier.
__global__ __launch_bounds__(256, 1) void k_lstm(
        const ushort* __restrict__ wbt, const float* __restrict__ rnn_in,
        const float* __restrict__ deltas, const int* __restrict__ h_lens,
        const float* __restrict__ W_ih, const float* __restrict__ b_lstm,
        uint* h_global, const int* __restrict__ sortedidx,
        float* __restrict__ last, unsigned int* bar) {
    __shared__ __align__(16) ushort w_lds[NW * KW];   // 137,280 B
    __shared__ __align__(16) ushort a_lds[RG * KW];   // 16,640 B (aliased as gates fp32[16][132])
    __shared__ float c_lds[RG * JW];                  // 2,112 B
    __shared__ int   rowg[RG];
    __shared__ int   hl_s[RG];

    const int tid = threadIdx.x;
    const int g   = blockIdx.x >> 4;
    const int s   = blockIdx.x & 15;

    if (tid < RG) {
        int o = sortedidx[g * RG + tid];
        rowg[tid] = o;
        hl_s[tid] = h_lens[o];
    }
    {   // stage weight slice: contiguous 132*260 dwords
        const uint* src = (const uint*)wbt + (size_t)s * NW * KD;
        uint* dst = (uint*)w_lds;
        for (int idx = tid; idx < NW * KD; idx += 256) dst[idx] = src[idx];
    }
    for (int idx = tid; idx < RG * JW; idx += 256) c_lds[idx] = 0.0f;
    __syncthreads();

    const int lane = tid & 63, wv = tid >> 6;
    const int l15 = lane & 15, quad = lane >> 4;
    const int ntile = (wv == 0) ? 3 : 2;
    int tiles[3] = { wv, wv + 4, wv + 8 };

    int myrows[4];
    #pragma unroll
    for (int r = 0; r < 4; r++) myrows[r] = rowg[quad * 4 + r];

    // W_ih / bias columns for this lane's n positions, held in registers
    float wihreg[3][CD1], breg[3];
    #pragma unroll
    for (int i = 0; i < 3; i++) {
        int nl = tiles[i] * 16 + l15;
        int jg = s * JW + (nl >> 2);
        bool ok = (i < ntile) && (nl < NW) && (jg < Hz);
        int col = (nl & 3) * Hz + jg;
        breg[i] = ok ? b_lstm[col] : 0.0f;
        #pragma unroll
        for (int q = 0; q < CD1; q++) wihreg[i][q] = ok ? W_ih[q * H4 + col] : 0.0f;
    }

    const int gmax = hl_s[0];
    uint* hg = h_global + (size_t)g * RG * KW;
    unsigned int myphase = 0;
    unsigned int* cnt = bar + (size_t)g * BARSTRIDE;
    unsigned int* ph  = bar + (size_t)(NG + g) * BARSTRIDE;

    for (int t = 0; t < gmax; t++) {
        // acc init = u_t @ W_ih + b — independent of h(t-1), hoisted before the barrier
        float uu[4][CD1];
        #pragma unroll
        for (int r = 0; r < 4; r++) {
            const float* up = rnn_in + ((size_t)myrows[r] * Tz + t) * CD1;
            #pragma unroll
            for (int q = 0; q < CD1; q++) uu[r][q] = up[q];
        }
        f32x4 acc[3];
        #pragma unroll
        for (int i = 0; i < 3; i++) {
            #pragma unroll
            for (int r = 0; r < 4; r++) {
                float a0 = breg[i];
                #pragma unroll
                for (int q = 0; q < CD1; q++) a0 += uu[r][q] * wihreg[i][q];
                acc[i][r] = a0;
            }
        }

        if (t > 0) {   // group barrier: h(t-1) from the 16 slice-WGs made visible
            __syncthreads();
            if (tid == 0) {
                unsigned int old = __hip_atomic_fetch_add(cnt, 1u, __ATOMIC_ACQ_REL, __HIP_MEMORY_SCOPE_AGENT);
                if (old == NSL - 1) {
                    __hip_atomic_store(cnt, 0u, __ATOMIC_RELAXED, __HIP_MEMORY_SCOPE_AGENT);
                    __hip_atomic_fetch_add(ph, 1u, __ATOMIC_RELEASE, __HIP_MEMORY_SCOPE_AGENT);
                } else {
                    while (__hip_atomic_load(ph, __ATOMIC_ACQUIRE, __HIP_MEMORY_SCOPE_AGENT) == myphase)
                        __builtin_amdgcn_s_sleep(1);
                }
            }
            myphase++;
            __syncthreads();
        }

        // read group h (packed bf16 hi/lo) — relaxed atomics pipeline, no inter-load waitcnt
        uint hpk[33];
        #pragma unroll
        for (int it = 0; it < 33; it++) {
            int idx = tid + it * 256;
            hpk[it] = (idx < RG * KW)
                ? __hip_atomic_load(hg + idx, __ATOMIC_RELAXED, __HIP_MEMORY_SCOPE_AGENT)
                : 0u;
        }

        // two MFMA passes: A = bf16_hi(h) then bf16_lo(h)  (weight-only bf16 error)
        #pragma unroll 1
        for (int pass = 0; pass < 2; pass++) {
            #pragma unroll
            for (int it = 0; it < 33; it++) {
                int idx = tid + it * 256;
                if (idx < RG * KW)
                    a_lds[idx] = pass ? (ushort)(hpk[it] >> 16) : (ushort)hpk[it];
            }
            __syncthreads();
            for (int kit = 0; kit < KIT; kit++) {
                int kq = kit * 32 + quad * 8;
                s16x8 af = {0, 0, 0, 0, 0, 0, 0, 0};
                if (kq < KW)
                    af = __builtin_bit_cast(s16x8,
                        *(const uint4*)((const uint*)a_lds + l15 * KD + kit * 16 + quad * 4));
                #pragma unroll
                for (int i = 0; i < 3; i++) {
                    if (i >= ntile) break;
                    int nl = tiles[i] * 16 + l15;
                    s16x8 bf = {0, 0, 0, 0, 0, 0, 0, 0};
                    if (nl < NW && kq < KW)
                        bf = __builtin_bit_cast(s16x8,
                            *(const uint4*)((const uint*)w_lds + nl * KD + kit * 16 + quad * 4));
                    acc[i] = __builtin_amdgcn_mfma_f32_16x16x32_bf16(af, bf, acc[i], 0, 0, 0);
                }
            }
            __syncthreads();
        }

        // gates (pre-activation) -> LDS, aliasing a_lds
        float* gates = (float*)a_lds;
        #pragma unroll
        for (int i = 0; i < 3; i++) {
            if (i >= ntile) break;
            int nl = tiles[i] * 16 + l15;
            if (nl < NW) {
                #pragma unroll
                for (int r = 0; r < 4; r++) gates[(quad * 4 + r) * NW + nl] = acc[i][r];
            }
        }
        __syncthreads();

        // elementwise cell update; h store packed+relaxed; capture 'last' at t == hl-1
        for (int p = tid; p < RG * JW; p += 256) {
            int m = p / JW, jj = p - m * JW;
            int jglob = s * JW + jj;
            if (jglob < Hz && t < hl_s[m]) {
                float4 gv = *(const float4*)(gates + m * NW + jj * 4);
                float ig = sigf(gv.x), fg = sigf(gv.y), gt = tanhf(gv.z), og = sigf(gv.w);
                float cp = c_lds[p];
                float cn = fg * cp + ig * gt;
                float hn = og * tanhf(cn);
                c_lds[p] = cn;
                int hidx = m * KW + jglob;
                if (t == hl_s[m] - 1) {
                    uint hpv = __hip_atomic_load(hg + hidx, __ATOMIC_RELAXED, __HIP_MEMORY_SCOPE_AGENT);
                    float hp = bf2f((ushort)hpv) + bf2f((ushort)(hpv >> 16));
                    int orig = rowg[m];
                    float d = deltas[(size_t)orig * Tz + t];
                    last[(size_t)orig * Hz + jglob] = (1.0f - d) * hp + d * hn;
                }
                ushort hi = f2bf(hn);
                ushort lo = f2bf(hn - bf2f(hi));
                __hip_atomic_store(hg + hidx, (uint)hi | ((uint)lo << 16),
                                   __ATOMIC_RELAXED, __HIP_MEMORY_SCOPE_AGENT);
            }
        }
        // no __threadfence: the barrier's ACQ_REL/RELEASE chain publishes the stores
    }
}

// final projection: (256,1040) @ (1040,8) + bias, one block per row
__global__ void k_dec3(const float* __restrict__ z2, const float* __restrict__ w,
                       const float* __restrict__ bias, float* __restrict__ out) {
    int m = blockIdx.x, tid = threadIdx.x;
    float p[8];
    #pragma unroll
    for (int n = 0; n < 8; n++) p[n] = 0.0f;
    for (int k = tid; k < Dz; k += 256) {
        float zv = z2[(size_t)m * Dz + k];
        #pragma unroll
        for (int n = 0; n < 8; n++) p[n] += zv * w[k * 8 + n];
    }
    __shared__ float red[256][8];
    #pragma unroll
    for (int n = 0; n < 8; n++) red[tid][n] = p[n];
    __syncthreads();
    for (int s2 = 128; s2 > 0; s2 >>= 1) {
        if (tid < s2) {
            #pragma unroll
            for (int n = 0; n < 8; n++) red[tid][n] += red[tid + s2][n];
        }
        __syncthreads();
    }
    if (tid < 8) out[m * 8 + tid] = red[0][tid] + bias[tid];
}

extern "C" void kernel_launch(void* const* d_in, const int* in_sizes, int n_in,
                              void* d_out, int out_size, void* d_ws, size_t ws_size,
                              hipStream_t stream) {
    const float* x       = (const float*)d_in[0];
    const float* rnn_inp = (const float*)d_in[1];
    const float* deltas  = (const float*)d_in[2];
    const int*   h_lens  = (const int*)  d_in[3];
    const float* enc_w1  = (const float*)d_in[4];
    const float* enc_b1  = (const float*)d_in[5];
    const float* enc_w2  = (const float*)d_in[6];
    const float* enc_b2  = (const float*)d_in[7];
    const float* enc_w3  = (const float*)d_in[8];
    const float* enc_b3  = (const float*)d_in[9];
    const float* W_ih    = (const float*)d_in[10];
    const float* W_hh    = (const float*)d_in[11];
    const float* b_lstm  = (const float*)d_in[12];
    const float* dec_w1  = (const float*)d_in[13];
    const float* dec_b1  = (const float*)d_in[14];
    const float* dec_w2  = (const float*)d_in[15];
    const float* dec_b2  = (const float*)d_in[16];
    const float* dec_w3  = (const float*)d_in[17];
    const float* dec_b3  = (const float*)d_in[18];
    (void)in_sizes; (void)n_in; (void)out_size; (void)ws_size;

    char* base = (char*)d_ws;
    size_t off = 0;
    auto alloc = [&](size_t bytes) { void* p = base + off; off = (off + bytes + 255) & ~(size_t)255; return p; };
    ushort* wbt      = (ushort*)alloc((size_t)NW * NSL * KW * 2);   // 2,196,480
    uint*   h_glob   = (uint*)  alloc((size_t)Bz * KW * 4);         // 532,480
    float*  hA       = (float*) alloc((size_t)Bz * KW * 4);
    float*  h1       = (float*) alloc((size_t)Bz * Ez * 4);
    float*  h2       = (float*) alloc((size_t)Bz * Ez * 4);
    float*  lastb    = (float*) alloc((size_t)Bz * Hz * 4);
    float*  z1       = (float*) alloc((size_t)Bz * Dz * 4);
    float*  z2       = (float*) alloc((size_t)Bz * Dz * 4);
    int*    sortedix = (int*)   alloc(Bz * 4);
    unsigned int* bar = (unsigned int*)alloc(2 * NG * BARSTRIDE * 4);
    float*  outp = (float*)d_out;

    hipMemsetAsync(bar, 0, 2 * NG * BARSTRIDE * 4, stream);
    k_sort<<<1, 256, 0, stream>>>(h_lens, sortedix);
    {
        int total = NW * NSL * KW;
        k_prep_w<<<(total + 255) / 256, 256, 0, stream>>>(W_hh, wbt);
    }

    k_mlp<Sz, Ez, 1><<<dim3(4, 64), 256, 0, stream>>>(x,  enc_w1, enc_b1, h1);
    k_mlp<Ez, Ez, 1><<<dim3(4, 64), 256, 0, stream>>>(h1, enc_w2, enc_b2, h2);
    k_enc3<<<dim3(2, 64), 256, 0, stream>>>(h2, enc_w3, enc_b3, x, hA);
    {
        int total = Bz * KW;
        k_hinit<<<(total + 255) / 256, 256, 0, stream>>>(hA, sortedix, h_glob);
    }

    {
        void* args[] = { (void*)&wbt, (void*)&rnn_inp, (void*)&deltas, (void*)&h_lens,
                         (void*)&W_ih, (void*)&b_lstm, (void*)&h_glob, (void*)&sortedix,
                         (void*)&lastb, (void*)&bar };
        hipLaunchCooperativeKernel(reinterpret_cast<void*>(k_lstm), dim3(NG * NSL), dim3(256),
                                   args, 0, stream);
    }

    k_mlp<Hz, Dz, 1><<<dim3(5, 64), 256, 0, stream>>>(lastb, dec_w1, dec_b1, z1);
    k_mlp<Dz, Dz, 1><<<dim3(5, 64), 256, 0, stream>>>(z1,   dec_w2, dec_b2, z2);
    k_dec3<<<Bz, 256, 0, stream>>>(z2, dec_w3, dec_b3, outp);
}

// Round 6
// 6522.688 us; speedup vs baseline: 4.7418x; 1.1799x over previous
//
#include <hip/hip_runtime.h>
#include <math.h>

#define Bz   256
#define Tz   512
#define Sz   8
#define CD1  5
#define Hz   520
#define H4   2080
#define Ez   1024
#define Dz   1040

// persistent LSTM geometry
#define NG   16     // row groups
#define NSL  16     // j-slices per group (NG*NSL = 256 WGs, 1 per CU)
#define RG   16     // rows per group
#define JW   33     // j per slice (16*33 = 528 >= 520)
#define NW   132    // gate columns per slice (JW*4)
#define KW   520    // K extent
#define KD   260    // dwords per K row (KW/2)
#define KIT  17     // k-iterations of 32 (ceil(520/32))
#define BARSTRIDE 32  // uints; 128B per flag to avoid line ping-pong

typedef float f32x4 __attribute__((ext_vector_type(4)));
typedef short s16x8 __attribute__((ext_vector_type(8)));

__device__ __forceinline__ ushort f2bf(float f) {
    uint u = __float_as_uint(f);
    uint r = (u + 0x7fffu + ((u >> 16) & 1u)) >> 16;
    return (ushort)r;
}
__device__ __forceinline__ float bf2f(ushort h) { return __uint_as_float(((uint)h) << 16); }
__device__ __forceinline__ float sigf(float v) { return 1.0f / (1.0f + expf(-v)); }

// rank-sort rows by h_len descending (ties by index) — O(n^2), one block
__global__ void k_sort(const int* __restrict__ hl, int* __restrict__ sortedidx) {
    __shared__ int s[Bz];
    int i = threadIdx.x;
    s[i] = hl[i];
    __syncthreads();
    int mine = s[i], rank = 0;
    for (int j = 0; j < Bz; j++) {
        int o = s[j];
        rank += (o > mine) || (o == mine && j < i);
    }
    sortedidx[rank] = i;
}

// W_hh -> bf16, layout wbt[n][k], n = j*4+gate (2112 rows incl. zero pad), k = 0..519
__global__ void k_prep_w(const float* __restrict__ whh, ushort* __restrict__ wbt) {
    int idx = blockIdx.x * 256 + threadIdx.x;
    if (idx >= NW * NSL * KW) return;
    int n = idx / KW, k = idx - n * KW;
    int j = n >> 2, gate = n & 3;
    float v = (j < Hz) ? whh[(size_t)k * H4 + gate * Hz + j] : 0.0f;
    wbt[idx] = f2bf(v);
}

// permute h0_stack rows into sorted order, packing fp32 -> (bf16_hi | bf16_lo<<16)
__global__ void k_hinit(const float* __restrict__ hA, const int* __restrict__ sortedidx,
                        uint* __restrict__ h_global) {
    int idx = blockIdx.x * 256 + threadIdx.x;
    if (idx >= Bz * KW) return;
    int rank = idx / KW, k = idx - rank * KW;
    float v = hA[(size_t)sortedidx[rank] * KW + k];
    ushort hi = f2bf(v);
    ushort lo = f2bf(v - bf2f(hi));
    h_global[idx] = (uint)hi | ((uint)lo << 16);
}

// out[m][n] = act( in[m][:] @ w[:][n] + bias[n] ), 4 rows/block, 256 threads over n
template<int K, int N, int ACT>
__global__ void k_mlp(const float* __restrict__ in, const float* __restrict__ w,
                      const float* __restrict__ bias, float* __restrict__ out) {
    int n  = blockIdx.x * 256 + threadIdx.x;
    int m0 = blockIdx.y * 4;
    if (n >= N) return;
    float acc[4];
    float bv = bias[n];
    #pragma unroll
    for (int i = 0; i < 4; i++) acc[i] = bv;
    for (int k = 0; k < K; k++) {
        float wv = w[k * N + n];
        #pragma unroll
        for (int i = 0; i < 4; i++) acc[i] += in[(m0 + i) * K + k] * wv;
    }
    #pragma unroll
    for (int i = 0; i < 4; i++) {
        float v = acc[i];
        out[(m0 + i) * N + n] = ACT ? tanhf(v) : v;
    }
}

// third encoder layer -> h-stack [x | h0], stride 520
__global__ void k_enc3(const float* __restrict__ h2, const float* __restrict__ w,
                       const float* __restrict__ bias, const float* __restrict__ x,
                       float* __restrict__ hstack) {
    int n  = blockIdx.x * 256 + threadIdx.x;   // 0..511
    int m0 = blockIdx.y * 4;
    float acc[4];
    float bv = bias[n];
    #pragma unroll
    for (int i = 0; i < 4; i++) acc[i] = bv;
    for (int k = 0; k < Ez; k++) {
        float wv = w[k * 512 + n];
        #pragma unroll
        for (int i = 0; i < 4; i++) acc[i] += h2[(m0 + i) * Ez + k] * wv;
    }
    #pragma unroll
    for (int i = 0; i < 4; i++) hstack[(m0 + i) * Hz + Sz + n] = acc[i];
    if (blockIdx.x == 0 && threadIdx.x < Sz) {
        #pragma unroll
        for (int i = 0; i < 4; i++)
            hstack[(m0 + i) * Hz + threadIdx.x] = x[(m0 + i) * Sz + threadIdx.x];
    }
}

// Persistent cooperative LSTM: 256 WGs (16 groups x 16 slices), weights resident in LDS.
// h exchanged as packed bf16 hi/lo via RELAXED agent-scope atomics.
// Sync: 16 per-slice monotone sequence flags (release store / acquire poll) — no RMW contention.
__global__ __launch_bounds__(256, 1) void k_lstm(
        const ushort* __restrict__ wbt, const float* __restrict__ rnn_in,
        const float* __restrict__ deltas, const int* __restrict__ h_lens,
        const float* __restrict__ W_ih, const float* __restrict__ b_lstm,
        uint* h_global, const int* __restrict__ sortedidx,
        float* __restrict__ last, unsigned int* bar) {
    __shared__ __align__(16) ushort w_lds[NW * KW];   // 137,280 B
    __shared__ __align__(16) ushort a_lds[RG * KW];   // 16,640 B (aliased as gates fp32[16][132])
    __shared__ float c_lds[RG * JW];                  // 2,112 B
    __shared__ int   rowg[RG];
    __shared__ int   hl_s[RG];

    const int tid = threadIdx.x;
    const int g   = blockIdx.x >> 4;
    const int s   = blockIdx.x & 15;

    if (tid < RG) {
        int o = sortedidx[g * RG + tid];
        rowg[tid] = o;
        hl_s[tid] = h_lens[o];
    }
    {   // stage weight slice: contiguous 132*260 dwords
        const uint* src = (const uint*)wbt + (size_t)s * NW * KD;
        uint* dst = (uint*)w_lds;
        for (int idx = tid; idx < NW * KD; idx += 256) dst[idx] = src[idx];
    }
    for (int idx = tid; idx < RG * JW; idx += 256) c_lds[idx] = 0.0f;
    __syncthreads();

    const int lane = tid & 63, wv = tid >> 6;
    const int l15 = lane & 15, quad = lane >> 4;
    const int ntile = (wv == 0) ? 3 : 2;
    int tiles[3] = { wv, wv + 4, wv + 8 };

    int myrows[4];
    #pragma unroll
    for (int r = 0; r < 4; r++) myrows[r] = rowg[quad * 4 + r];

    // W_ih / bias columns for this lane's n positions, held in registers
    float wihreg[3][CD1], breg[3];
    #pragma unroll
    for (int i = 0; i < 3; i++) {
        int nl = tiles[i] * 16 + l15;
        int jg = s * JW + (nl >> 2);
        bool ok = (i < ntile) && (nl < NW) && (jg < Hz);
        int col = (nl & 3) * Hz + (jg < Hz ? jg : 0);
        breg[i] = ok ? b_lstm[col] : 0.0f;
        #pragma unroll
        for (int q = 0; q < CD1; q++) wihreg[i][q] = ok ? W_ih[q * H4 + col] : 0.0f;
    }

    const int gmax = hl_s[0];
    uint* hg = h_global + (size_t)g * RG * KW;
    unsigned int* flg = bar + (size_t)(g * NSL) * BARSTRIDE;   // 16 flags, 128B apart

    for (int t = 0; t < gmax; t++) {
        // acc init = u_t @ W_ih + b — independent of h(t-1), issued before the wait
        float uu[4][CD1];
        #pragma unroll
        for (int r = 0; r < 4; r++) {
            const float* up = rnn_in + ((size_t)myrows[r] * Tz + t) * CD1;
            #pragma unroll
            for (int q = 0; q < CD1; q++) uu[r][q] = up[q];
        }
        f32x4 acc[3];
        #pragma unroll
        for (int i = 0; i < 3; i++) {
            #pragma unroll
            for (int r = 0; r < 4; r++) {
                float a0 = breg[i];
                #pragma unroll
                for (int q = 0; q < CD1; q++) a0 += uu[r][q] * wihreg[i][q];
                acc[i][r] = a0;
            }
        }

        if (t > 0) {   // wait until all 16 slices have published h(t-1): flag[s'] >= t
            int ready;
            do {
                int ok = 1;
                if (tid < NSL)
                    ok = (__hip_atomic_load(flg + tid * BARSTRIDE, __ATOMIC_ACQUIRE,
                                            __HIP_MEMORY_SCOPE_AGENT) >= (unsigned)t);
                ready = __syncthreads_and(ok);
                if (!ready) __builtin_amdgcn_s_sleep(2);
            } while (!ready);
        }

        // read group h (packed bf16 hi/lo) — relaxed atomics pipeline, no inter-load waitcnt
        uint hpk[33];
        #pragma unroll
        for (int it = 0; it < 33; it++) {
            int idx = tid + it * 256;
            hpk[it] = (idx < RG * KW)
                ? __hip_atomic_load(hg + idx, __ATOMIC_RELAXED, __HIP_MEMORY_SCOPE_AGENT)
                : 0u;
        }

        // two MFMA passes: A = bf16_hi(h) then bf16_lo(h)  (weight-only bf16 error)
        #pragma unroll 1
        for (int pass = 0; pass < 2; pass++) {
            #pragma unroll
            for (int it = 0; it < 33; it++) {
                int idx = tid + it * 256;
                if (idx < RG * KW)
                    a_lds[idx] = pass ? (ushort)(hpk[it] >> 16) : (ushort)hpk[it];
            }
            __syncthreads();
            for (int kit = 0; kit < KIT; kit++) {
                int kq = kit * 32 + quad * 8;
                s16x8 af = {0, 0, 0, 0, 0, 0, 0, 0};
                if (kq < KW)
                    af = __builtin_bit_cast(s16x8,
                        *(const uint4*)((const uint*)a_lds + l15 * KD + kit * 16 + quad * 4));
                #pragma unroll
                for (int i = 0; i < 3; i++) {
                    if (i >= ntile) break;
                    int nl = tiles[i] * 16 + l15;
                    s16x8 bf = {0, 0, 0, 0, 0, 0, 0, 0};
                    if (nl < NW && kq < KW)
                        bf = __builtin_bit_cast(s16x8,
                            *(const uint4*)((const uint*)w_lds + nl * KD + kit * 16 + quad * 4));
                    acc[i] = __builtin_amdgcn_mfma_f32_16x16x32_bf16(af, bf, acc[i], 0, 0, 0);
                }
            }
            __syncthreads();
        }

        // gates (pre-activation) -> LDS, aliasing a_lds
        float* gates = (float*)a_lds;
        #pragma unroll
        for (int i = 0; i < 3; i++) {
            if (i >= ntile) break;
            int nl = tiles[i] * 16 + l15;
            if (nl < NW) {
                #pragma unroll
                for (int r = 0; r < 4; r++) gates[(quad * 4 + r) * NW + nl] = acc[i][r];
            }
        }
        __syncthreads();

        // elementwise cell update; h store packed+relaxed; capture 'last' at t == hl-1
        for (int p = tid; p < RG * JW; p += 256) {
            int m = p / JW, jj = p - m * JW;
            int jglob = s * JW + jj;
            if (jglob < Hz && t < hl_s[m]) {
                float4 gv = *(const float4*)(gates + m * NW + jj * 4);
                float ig = sigf(gv.x), fg = sigf(gv.y), gt = tanhf(gv.z), og = sigf(gv.w);
                float cp = c_lds[p];
                float cn = fg * cp + ig * gt;
                float hn = og * tanhf(cn);
                c_lds[p] = cn;
                int hidx = m * KW + jglob;
                if (t == hl_s[m] - 1) {
                    uint hpv = __hip_atomic_load(hg + hidx, __ATOMIC_RELAXED, __HIP_MEMORY_SCOPE_AGENT);
                    float hp = bf2f((ushort)hpv) + bf2f((ushort)(hpv >> 16));
                    int orig = rowg[m];
                    float d = deltas[(size_t)orig * Tz + t];
                    last[(size_t)orig * Hz + jglob] = (1.0f - d) * hp + d * hn;
                }
                ushort hi = f2bf(hn);
                ushort lo = f2bf(hn - bf2f(hi));
                __hip_atomic_store(hg + hidx, (uint)hi | ((uint)lo << 16),
                                   __ATOMIC_RELAXED, __HIP_MEMORY_SCOPE_AGENT);
            }
        }

        // publish h(t): release store orders the relaxed h stores (after __syncthreads HB)
        __syncthreads();
        if (tid == 0)
            __hip_atomic_store(flg + s * BARSTRIDE, (unsigned)(t + 1),
                               __ATOMIC_RELEASE, __HIP_MEMORY_SCOPE_AGENT);
    }
}

// final projection: (256,1040) @ (1040,8) + bias, one block per row
__global__ void k_dec3(const float* __restrict__ z2, const float* __restrict__ w,
                       const float* __restrict__ bias, float* __restrict__ out) {
    int m = blockIdx.x, tid = threadIdx.x;
    float p[8];
    #pragma unroll
    for (int n = 0; n < 8; n++) p[n] = 0.0f;
    for (int k = tid; k < Dz; k += 256) {
        float zv = z2[(size_t)m * Dz + k];
        #pragma unroll
        for (int n = 0; n < 8; n++) p[n] += zv * w[k * 8 + n];
    }
    __shared__ float red[256][8];
    #pragma unroll
    for (int n = 0; n < 8; n++) red[tid][n] = p[n];
    __syncthreads();
    for (int s2 = 128; s2 > 0; s2 >>= 1) {
        if (tid < s2) {
            #pragma unroll
            for (int n = 0; n < 8; n++) red[tid][n] += red[tid + s2][n];
        }
        __syncthreads();
    }
    if (tid < 8) out[m * 8 + tid] = red[0][tid] + bias[tid];
}

extern "C" void kernel_launch(void* const* d_in, const int* in_sizes, int n_in,
                              void* d_out, int out_size, void* d_ws, size_t ws_size,
                              hipStream_t stream) {
    const float* x       = (const float*)d_in[0];
    const float* rnn_inp = (const float*)d_in[1];
    const float* deltas  = (const float*)d_in[2];
    const int*   h_lens  = (const int*)  d_in[3];
    const float* enc_w1  = (const float*)d_in[4];
    const float* enc_b1  = (const float*)d_in[5];
    const float* enc_w2  = (const float*)d_in[6];
    const float* enc_b2  = (const float*)d_in[7];
    const float* enc_w3  = (const float*)d_in[8];
    const float* enc_b3  = (const float*)d_in[9];
    const float* W_ih    = (const float*)d_in[10];
    const float* W_hh    = (const float*)d_in[11];
    const float* b_lstm  = (const float*)d_in[12];
    const float* dec_w1  = (const float*)d_in[13];
    const float* dec_b1  = (const float*)d_in[14];
    const float* dec_w2  = (const float*)d_in[15];
    const float* dec_b2  = (const float*)d_in[16];
    const float* dec_w3  = (const float*)d_in[17];
    const float* dec_b3  = (const float*)d_in[18];
    (void)in_sizes; (void)n_in; (void)out_size; (void)ws_size;

    char* base = (char*)d_ws;
    size_t off = 0;
    auto alloc = [&](size_t bytes) { void* p = base + off; off = (off + bytes + 255) & ~(size_t)255; return p; };
    ushort* wbt      = (ushort*)alloc((size_t)NW * NSL * KW * 2);   // 2,196,480
    uint*   h_glob   = (uint*)  alloc((size_t)Bz * KW * 4);         // 532,480
    float*  hA       = (float*) alloc((size_t)Bz * KW * 4);
    float*  h1       = (float*) alloc((size_t)Bz * Ez * 4);
    float*  h2       = (float*) alloc((size_t)Bz * Ez * 4);
    float*  lastb    = (float*) alloc((size_t)Bz * Hz * 4);
    float*  z1       = (float*) alloc((size_t)Bz * Dz * 4);
    float*  z2       = (float*) alloc((size_t)Bz * Dz * 4);
    int*    sortedix = (int*)   alloc(Bz * 4);
    unsigned int* bar = (unsigned int*)alloc((size_t)NG * NSL * BARSTRIDE * 4);
    float*  outp = (float*)d_out;

    hipMemsetAsync(bar, 0, (size_t)NG * NSL * BARSTRIDE * 4, stream);
    k_sort<<<1, 256, 0, stream>>>(h_lens, sortedix);
    {
        int total = NW * NSL * KW;
        k_prep_w<<<(total + 255) / 256, 256, 0, stream>>>(W_hh, wbt);
    }

    k_mlp<Sz, Ez, 1><<<dim3(4, 64), 256, 0, stream>>>(x,  enc_w1, enc_b1, h1);
    k_mlp<Ez, Ez, 1><<<dim3(4, 64), 256, 0, stream>>>(h1, enc_w2, enc_b2, h2);
    k_enc3<<<dim3(2, 64), 256, 0, stream>>>(h2, enc_w3, enc_b3, x, hA);
    {
        int total = Bz * KW;
        k_hinit<<<(total + 255) / 256, 256, 0, stream>>>(hA, sortedix, h_glob);
    }

    {
        void* args[] = { (void*)&wbt, (void*)&rnn_inp, (void*)&deltas, (void*)&h_lens,
                         (void*)&W_ih, (void*)&b_lstm, (void*)&h_glob, (void*)&sortedix,
                         (void*)&lastb, (void*)&bar };
        hipLaunchCooperativeKernel(reinterpret_cast<void*>(k_lstm), dim3(NG * NSL), dim3(256),
                                   args, 0, stream);
    }

    k_mlp<Hz, Dz, 1><<<dim3(5, 64), 256, 0, stream>>>(lastb, dec_w1, dec_b1, z1);
    k_mlp<Dz, Dz, 1><<<dim3(5, 64), 256, 0, stream>>>(z1,   dec_w2, dec_b2, z2);
    k_dec3<<<Bz, 256, 0, stream>>>(z2, dec_w3, dec_b3, outp);
}

// Round 7
// 4556.421 us; speedup vs baseline: 6.7881x; 1.4315x over previous
//
#include <hip/hip_runtime.h>
#include <math.h>

#define Bz   256
#define Tz   512
#define Sz   8
#define CD1  5
#define Hz   520
#define H4   2080
#define Ez   1024
#define Dz   1040

// persistent LSTM geometry
#define NG   16     // row groups
#define NSL  16     // j-slices per group (NG*NSL = 256 WGs, 1 per CU)
#define RG   16     // rows per group
#define JW   34     // j per slice (16*34 = 544 >= 520; even -> clean dword ownership)
#define NW   136    // gate columns per slice (JW*4)
#define KW   520    // K extent
#define KD   260    // dwords per K row (KW/2, bf16-packed)
#define KIT  17     // k-iterations of 32 (ceil(520/32))
#define HGD  4160   // dwords of packed h per group (RG*KW/2)
#define BARSTRIDE 32  // uints; 128B per flag to avoid line ping-pong

typedef float f32x4 __attribute__((ext_vector_type(4)));
typedef short s16x8 __attribute__((ext_vector_type(8)));

__device__ __forceinline__ ushort f2bf(float f) {
    uint u = __float_as_uint(f);
    uint r = (u + 0x7fffu + ((u >> 16) & 1u)) >> 16;
    return (ushort)r;
}
__device__ __forceinline__ float bf2f(ushort h) { return __uint_as_float(((uint)h) << 16); }
__device__ __forceinline__ float sigf(float v) { return 1.0f / (1.0f + expf(-v)); }

// rank-sort rows by h_len descending (ties by index) — O(n^2), one block
__global__ void k_sort(const int* __restrict__ hl, int* __restrict__ sortedidx) {
    __shared__ int s[Bz];
    int i = threadIdx.x;
    s[i] = hl[i];
    __syncthreads();
    int mine = s[i], rank = 0;
    for (int j = 0; j < Bz; j++) {
        int o = s[j];
        rank += (o > mine) || (o == mine && j < i);
    }
    sortedidx[rank] = i;
}

// W_hh -> bf16, layout wbt[n][k], n_global = s*NW + nl; j = n_global>>2 (= s*JW + nl>>2), gate = n&3
__global__ void k_prep_w(const float* __restrict__ whh, ushort* __restrict__ wbt) {
    int idx = blockIdx.x * 256 + threadIdx.x;
    if (idx >= NW * NSL * KW) return;
    int n = idx / KW, k = idx - n * KW;
    int j = n >> 2, gate = n & 3;
    float v = (j < Hz) ? whh[(size_t)k * H4 + gate * Hz + j] : 0.0f;
    wbt[idx] = f2bf(v);
}

// permute h0_stack rows into sorted order, bf16-packed: dword kd = (h[2kd] | h[2kd+1]<<16)
__global__ void k_hinit(const float* __restrict__ hA, const int* __restrict__ sortedidx,
                        uint* __restrict__ h_global) {
    int idx = blockIdx.x * 256 + threadIdx.x;
    if (idx >= Bz * KW / 2) return;
    int rank = idx / KD, kd = idx - rank * KD;
    const float* src = hA + (size_t)sortedidx[rank] * KW + 2 * kd;
    h_global[idx] = (uint)f2bf(src[0]) | ((uint)f2bf(src[1]) << 16);
}

// out[m][n] = act( in[m][:] @ w[:][n] + bias[n] ), 4 rows/block, 256 threads over n
template<int K, int N, int ACT>
__global__ void k_mlp(const float* __restrict__ in, const float* __restrict__ w,
                      const float* __restrict__ bias, float* __restrict__ out) {
    int n  = blockIdx.x * 256 + threadIdx.x;
    int m0 = blockIdx.y * 4;
    if (n >= N) return;
    float acc[4];
    float bv = bias[n];
    #pragma unroll
    for (int i = 0; i < 4; i++) acc[i] = bv;
    for (int k = 0; k < K; k++) {
        float wv = w[k * N + n];
        #pragma unroll
        for (int i = 0; i < 4; i++) acc[i] += in[(m0 + i) * K + k] * wv;
    }
    #pragma unroll
    for (int i = 0; i < 4; i++) {
        float v = acc[i];
        out[(m0 + i) * N + n] = ACT ? tanhf(v) : v;
    }
}

// third encoder layer -> h-stack [x | h0], stride 520
__global__ void k_enc3(const float* __restrict__ h2, const float* __restrict__ w,
                       const float* __restrict__ bias, const float* __restrict__ x,
                       float* __restrict__ hstack) {
    int n  = blockIdx.x * 256 + threadIdx.x;   // 0..511
    int m0 = blockIdx.y * 4;
    float acc[4];
    float bv = bias[n];
    #pragma unroll
    for (int i = 0; i < 4; i++) acc[i] = bv;
    for (int k = 0; k < Ez; k++) {
        float wv = w[k * 512 + n];
        #pragma unroll
        for (int i = 0; i < 4; i++) acc[i] += h2[(m0 + i) * Ez + k] * wv;
    }
    #pragma unroll
    for (int i = 0; i < 4; i++) hstack[(m0 + i) * Hz + Sz + n] = acc[i];
    if (blockIdx.x == 0 && threadIdx.x < Sz) {
        #pragma unroll
        for (int i = 0; i < 4; i++)
            hstack[(m0 + i) * Hz + threadIdx.x] = x[(m0 + i) * Sz + threadIdx.x];
    }
}

// Persistent cooperative LSTM: 256 WGs (16 groups x 16 slices), weights resident in LDS.
// h exchanged as bf16 via RELAXED agent-scope atomics; single bf16 MFMA pass.
// Sync: 16 per-slice monotone sequence flags (release store / acquire poll).
__global__ __launch_bounds__(256, 1) void k_lstm(
        const ushort* __restrict__ wbt, const float* __restrict__ rnn_in,
        const float* __restrict__ deltas, const int* __restrict__ h_lens,
        const float* __restrict__ W_ih, const float* __restrict__ b_lstm,
        ushort* h_global, const int* __restrict__ sortedidx,
        float* __restrict__ last, unsigned int* bar) {
    __shared__ __align__(16) ushort w_lds[NW * KW];   // 141,440 B
    __shared__ __align__(16) ushort a_lds[RG * KW];   // 16,640 B (aliased as gates fp32[16][136])
    __shared__ float c_lds[RG * JW];                  // 2,176 B
    __shared__ int   rowg[RG];
    __shared__ int   hl_s[RG];

    const int tid = threadIdx.x;
    const int g   = blockIdx.x >> 4;
    const int s   = blockIdx.x & 15;

    if (tid < RG) {
        int o = sortedidx[g * RG + tid];
        rowg[tid] = o;
        hl_s[tid] = h_lens[o];
    }
    {   // stage weight slice: contiguous 136*260 dwords
        const uint* src = (const uint*)wbt + (size_t)s * NW * KD;
        uint* dst = (uint*)w_lds;
        for (int idx = tid; idx < NW * KD; idx += 256) dst[idx] = src[idx];
    }
    for (int idx = tid; idx < RG * JW; idx += 256) c_lds[idx] = 0.0f;
    __syncthreads();

    const int lane = tid & 63, wv = tid >> 6;
    const int l15 = lane & 15, quad = lane >> 4;
    const int ntile = (wv == 0) ? 3 : 2;
    int tiles[3] = { wv, wv + 4, wv + 8 };

    int myrows[4];
    #pragma unroll
    for (int r = 0; r < 4; r++) myrows[r] = rowg[quad * 4 + r];

    // W_ih / bias columns for this lane's n positions, held in registers
    float wihreg[3][CD1], breg[3];
    #pragma unroll
    for (int i = 0; i < 3; i++) {
        int nl = tiles[i] * 16 + l15;
        int jg = s * JW + (nl >> 2);
        bool ok = (i < ntile) && (nl < NW) && (jg < Hz);
        int col = (nl & 3) * Hz + (jg < Hz ? jg : 0);
        breg[i] = ok ? b_lstm[col] : 0.0f;
        #pragma unroll
        for (int q = 0; q < CD1; q++) wihreg[i][q] = ok ? W_ih[q * H4 + col] : 0.0f;
    }

    const int gmax = hl_s[0];
    ushort* hg16 = h_global + (size_t)g * RG * KW;
    const uint* hg32 = (const uint*)hg16;
    unsigned int* flg = bar + (size_t)(g * NSL) * BARSTRIDE;   // 16 flags, 128B apart

    for (int t = 0; t < gmax; t++) {
        // acc init = u_t @ W_ih + b — independent of h(t-1), issued before the wait
        float uu[4][CD1];
        #pragma unroll
        for (int r = 0; r < 4; r++) {
            const float* up = rnn_in + ((size_t)myrows[r] * Tz + t) * CD1;
            #pragma unroll
            for (int q = 0; q < CD1; q++) uu[r][q] = up[q];
        }
        f32x4 acc[3];
        #pragma unroll
        for (int i = 0; i < 3; i++) {
            #pragma unroll
            for (int r = 0; r < 4; r++) {
                float a0 = breg[i];
                #pragma unroll
                for (int q = 0; q < CD1; q++) a0 += uu[r][q] * wihreg[i][q];
                acc[i][r] = a0;
            }
        }

        if (t > 0) {   // wait until all 16 slices have published h(t-1): flag[s'] >= t
            int ready;
            do {
                int ok = 1;
                if (tid < NSL)
                    ok = (__hip_atomic_load(flg + tid * BARSTRIDE, __ATOMIC_ACQUIRE,
                                            __HIP_MEMORY_SCOPE_AGENT) >= (unsigned)t);
                ready = __syncthreads_and(ok);
                if (!ready) __builtin_amdgcn_s_sleep(2);
            } while (!ready);
        }

        // read group h (packed bf16 pairs) — relaxed atomics pipeline
        uint hpk[17];
        #pragma unroll
        for (int it = 0; it < 17; it++) {
            int idx = tid + it * 256;
            hpk[it] = (idx < HGD)
                ? __hip_atomic_load(hg32 + idx, __ATOMIC_RELAXED, __HIP_MEMORY_SCOPE_AGENT)
                : 0u;
        }

        // stage A (single bf16 plane) and run the MFMA k-loop
        #pragma unroll
        for (int it = 0; it < 17; it++) {
            int idx = tid + it * 256;
            if (idx < HGD) ((uint*)a_lds)[idx] = hpk[it];
        }
        __syncthreads();
        for (int kit = 0; kit < KIT; kit++) {
            int kq = kit * 32 + quad * 8;
            s16x8 af = {0, 0, 0, 0, 0, 0, 0, 0};
            if (kq < KW)
                af = __builtin_bit_cast(s16x8,
                    *(const uint4*)((const uint*)a_lds + l15 * KD + kit * 16 + quad * 4));
            #pragma unroll
            for (int i = 0; i < 3; i++) {
                if (i >= ntile) break;
                int nl = tiles[i] * 16 + l15;
                s16x8 bf = {0, 0, 0, 0, 0, 0, 0, 0};
                if (nl < NW && kq < KW)
                    bf = __builtin_bit_cast(s16x8,
                        *(const uint4*)((const uint*)w_lds + nl * KD + kit * 16 + quad * 4));
                acc[i] = __builtin_amdgcn_mfma_f32_16x16x32_bf16(af, bf, acc[i], 0, 0, 0);
            }
        }
        __syncthreads();

        // gates (pre-activation) -> LDS, aliasing a_lds
        float* gates = (float*)a_lds;
        #pragma unroll
        for (int i = 0; i < 3; i++) {
            if (i >= ntile) break;
            int nl = tiles[i] * 16 + l15;
            if (nl < NW) {
                #pragma unroll
                for (int r = 0; r < 4; r++) gates[(quad * 4 + r) * NW + nl] = acc[i][r];
            }
        }
        __syncthreads();

        // elementwise cell update; h store bf16+relaxed; capture 'last' at t == hl-1
        for (int p = tid; p < RG * JW; p += 256) {
            int m = p / JW, jj = p - m * JW;
            int jglob = s * JW + jj;
            if (jglob < Hz && t < hl_s[m]) {
                float4 gv = *(const float4*)(gates + m * NW + jj * 4);
                float ig = sigf(gv.x), fg = sigf(gv.y), gt = tanhf(gv.z), og = sigf(gv.w);
                float cp = c_lds[p];
                float cn = fg * cp + ig * gt;
                float hn = og * tanhf(cn);
                c_lds[p] = cn;
                int hidx = m * KW + jglob;
                if (t == hl_s[m] - 1) {
                    ushort hpv = __hip_atomic_load(hg16 + hidx, __ATOMIC_RELAXED, __HIP_MEMORY_SCOPE_AGENT);
                    float hp = bf2f(hpv);
                    int orig = rowg[m];
                    float d = deltas[(size_t)orig * Tz + t];
                    last[(size_t)orig * Hz + jglob] = (1.0f - d) * hp + d * hn;
                }
                __hip_atomic_store(hg16 + hidx, f2bf(hn),
                                   __ATOMIC_RELAXED, __HIP_MEMORY_SCOPE_AGENT);
            }
        }

        // publish h(t): release store orders the relaxed h stores (after __syncthreads HB)
        __syncthreads();
        if (tid == 0)
            __hip_atomic_store(flg + s * BARSTRIDE, (unsigned)(t + 1),
                               __ATOMIC_RELEASE, __HIP_MEMORY_SCOPE_AGENT);
    }
}

// final projection: (256,1040) @ (1040,8) + bias, one block per row
__global__ void k_dec3(const float* __restrict__ z2, const float* __restrict__ w,
                       const float* __restrict__ bias, float* __restrict__ out) {
    int m = blockIdx.x, tid = threadIdx.x;
    float p[8];
    #pragma unroll
    for (int n = 0; n < 8; n++) p[n] = 0.0f;
    for (int k = tid; k < Dz; k += 256) {
        float zv = z2[(size_t)m * Dz + k];
        #pragma unroll
        for (int n = 0; n < 8; n++) p[n] += zv * w[k * 8 + n];
    }
    __shared__ float red[256][8];
    #pragma unroll
    for (int n = 0; n < 8; n++) red[tid][n] = p[n];
    __syncthreads();
    for (int s2 = 128; s2 > 0; s2 >>= 1) {
        if (tid < s2) {
            #pragma unroll
            for (int n = 0; n < 8; n++) red[tid][n] += red[tid + s2][n];
        }
        __syncthreads();
    }
    if (tid < 8) out[m * 8 + tid] = red[0][tid] + bias[tid];
}

extern "C" void kernel_launch(void* const* d_in, const int* in_sizes, int n_in,
                              void* d_out, int out_size, void* d_ws, size_t ws_size,
                              hipStream_t stream) {
    const float* x       = (const float*)d_in[0];
    const float* rnn_inp = (const float*)d_in[1];
    const float* deltas  = (const float*)d_in[2];
    const int*   h_lens  = (const int*)  d_in[3];
    const float* enc_w1  = (const float*)d_in[4];
    const float* enc_b1  = (const float*)d_in[5];
    const float* enc_w2  = (const float*)d_in[6];
    const float* enc_b2  = (const float*)d_in[7];
    const float* enc_w3  = (const float*)d_in[8];
    const float* enc_b3  = (const float*)d_in[9];
    const float* W_ih    = (const float*)d_in[10];
    const float* W_hh    = (const float*)d_in[11];
    const float* b_lstm  = (const float*)d_in[12];
    const float* dec_w1  = (const float*)d_in[13];
    const float* dec_b1  = (const float*)d_in[14];
    const float* dec_w2  = (const float*)d_in[15];
    const float* dec_b2  = (const float*)d_in[16];
    const float* dec_w3  = (const float*)d_in[17];
    const float* dec_b3  = (const float*)d_in[18];
    (void)in_sizes; (void)n_in; (void)out_size; (void)ws_size;

    char* base = (char*)d_ws;
    size_t off = 0;
    auto alloc = [&](size_t bytes) { void* p = base + off; off = (off + bytes + 255) & ~(size_t)255; return p; };
    ushort* wbt      = (ushort*)alloc((size_t)NW * NSL * KW * 2);   // 2,263,040
    ushort* h_glob   = (ushort*)alloc((size_t)Bz * KW * 2);         // 266,240
    float*  hA       = (float*) alloc((size_t)Bz * KW * 4);
    float*  h1       = (float*) alloc((size_t)Bz * Ez * 4);
    float*  h2       = (float*) alloc((size_t)Bz * Ez * 4);
    float*  lastb    = (float*) alloc((size_t)Bz * Hz * 4);
    float*  z1       = (float*) alloc((size_t)Bz * Dz * 4);
    float*  z2       = (float*) alloc((size_t)Bz * Dz * 4);
    int*    sortedix = (int*)   alloc(Bz * 4);
    unsigned int* bar = (unsigned int*)alloc((size_t)NG * NSL * BARSTRIDE * 4);
    float*  outp = (float*)d_out;

    hipMemsetAsync(bar, 0, (size_t)NG * NSL * BARSTRIDE * 4, stream);
    k_sort<<<1, 256, 0, stream>>>(h_lens, sortedix);
    {
        int total = NW * NSL * KW;
        k_prep_w<<<(total + 255) / 256, 256, 0, stream>>>(W_hh, wbt);
    }

    k_mlp<Sz, Ez, 1><<<dim3(4, 64), 256, 0, stream>>>(x,  enc_w1, enc_b1, h1);
    k_mlp<Ez, Ez, 1><<<dim3(4, 64), 256, 0, stream>>>(h1, enc_w2, enc_b2, h2);
    k_enc3<<<dim3(2, 64), 256, 0, stream>>>(h2, enc_w3, enc_b3, x, hA);
    {
        int total = Bz * KW / 2;
        k_hinit<<<(total + 255) / 256, 256, 0, stream>>>(hA, sortedix, (uint*)h_glob);
    }

    {
        void* args[] = { (void*)&wbt, (void*)&rnn_inp, (void*)&deltas, (void*)&h_lens,
                         (void*)&W_ih, (void*)&b_lstm, (void*)&h_glob, (void*)&sortedix,
                         (void*)&lastb, (void*)&bar };
        hipLaunchCooperativeKernel(reinterpret_cast<void*>(k_lstm), dim3(NG * NSL), dim3(256),
                                   args, 0, stream);
    }

    k_mlp<Hz, Dz, 1><<<dim3(5, 64), 256, 0, stream>>>(lastb, dec_w1, dec_b1, z1);
    k_mlp<Dz, Dz, 1><<<dim3(5, 64), 256, 0, stream>>>(z1,   dec_w2, dec_b2, z2);
    k_dec3<<<Bz, 256, 0, stream>>>(z2, dec_w3, dec_b3, outp);
}

// Round 9
// 3193.500 us; speedup vs baseline: 9.6851x; 1.4268x over previous
//
#include <hip/hip_runtime.h>
#include <math.h>

#define Bz   256
#define Tz   512
#define Sz   8
#define CD1  5
#define Hz   520
#define H4   2080
#define Ez   1024
#define Dz   1040

// persistent LSTM geometry
#define NG   16     // row groups
#define NSL  16     // j-slices per group (NG*NSL = 256 WGs, 1 per CU)
#define RG   16     // rows per group
#define JW   34     // j per slice (16*34 = 544 >= 520)
#define NW   136    // gate columns per slice (JW*4)
#define KW   520    // K extent
#define KD   260    // dwords per K row (KW/2, bf16-packed)
#define KIT  17     // k-iterations of 32 (ceil(520/32))
#define HGD  4160   // dwords of packed h per group (RG*KW/2)
#define NTHR 512    // threads per WG (8 waves; 2 waves/SIMD hides LDS latency)
#define BARSTRIDE 32  // uints; 128B per flag to avoid line ping-pong

typedef float f32x4 __attribute__((ext_vector_type(4)));
typedef short s16x8 __attribute__((ext_vector_type(8)));

__device__ __forceinline__ ushort f2bf(float f) {
    uint u = __float_as_uint(f);
    uint r = (u + 0x7fffu + ((u >> 16) & 1u)) >> 16;
    return (ushort)r;
}
__device__ __forceinline__ float bf2f(ushort h) { return __uint_as_float(((uint)h) << 16); }
__device__ __forceinline__ float sigf(float v) { return 1.0f / (1.0f + expf(-v)); }

// rank-sort rows by h_len descending (ties by index) — O(n^2), one block
__global__ void k_sort(const int* __restrict__ hl, int* __restrict__ sortedidx) {
    __shared__ int s[Bz];
    int i = threadIdx.x;
    s[i] = hl[i];
    __syncthreads();
    int mine = s[i], rank = 0;
    for (int j = 0; j < Bz; j++) {
        int o = s[j];
        rank += (o > mine) || (o == mine && j < i);
    }
    sortedidx[rank] = i;
}

// W_hh -> bf16, layout wbt[n][k], n_global = s*NW + nl; j = n_global>>2, gate = n&3
__global__ void k_prep_w(const float* __restrict__ whh, ushort* __restrict__ wbt) {
    int idx = blockIdx.x * 256 + threadIdx.x;
    if (idx >= NW * NSL * KW) return;
    int n = idx / KW, k = idx - n * KW;
    int j = n >> 2, gate = n & 3;
    float v = (j < Hz) ? whh[(size_t)k * H4 + gate * Hz + j] : 0.0f;
    wbt[idx] = f2bf(v);
}

// permute h0_stack rows into sorted order, bf16-packed, into h buffer 1 (read at t=0)
__global__ void k_hinit(const float* __restrict__ hA, const int* __restrict__ sortedidx,
                        uint* __restrict__ h_buf1) {
    int idx = blockIdx.x * 256 + threadIdx.x;
    if (idx >= Bz * KW / 2) return;
    int rank = idx / KD, kd = idx - rank * KD;
    const float* src = hA + (size_t)sortedidx[rank] * KW + 2 * kd;
    h_buf1[idx] = (uint)f2bf(src[0]) | ((uint)f2bf(src[1]) << 16);
}

// out[m][n] = act( in[m][:] @ w[:][n] + bias[n] ), 4 rows/block, 256 threads over n
template<int K, int N, int ACT>
__global__ void k_mlp(const float* __restrict__ in, const float* __restrict__ w,
                      const float* __restrict__ bias, float* __restrict__ out) {
    int n  = blockIdx.x * 256 + threadIdx.x;
    int m0 = blockIdx.y * 4;
    if (n >= N) return;
    float acc[4];
    float bv = bias[n];
    #pragma unroll
    for (int i = 0; i < 4; i++) acc[i] = bv;
    for (int k = 0; k < K; k++) {
        float wv = w[k * N + n];
        #pragma unroll
        for (int i = 0; i < 4; i++) acc[i] += in[(m0 + i) * K + k] * wv;
    }
    #pragma unroll
    for (int i = 0; i < 4; i++) {
        float v = acc[i];
        out[(m0 + i) * N + n] = ACT ? tanhf(v) : v;
    }
}

// third encoder layer -> h-stack [x | h0], stride 520
__global__ void k_enc3(const float* __restrict__ h2, const float* __restrict__ w,
                       const float* __restrict__ bias, const float* __restrict__ x,
                       float* __restrict__ hstack) {
    int n  = blockIdx.x * 256 + threadIdx.x;   // 0..511
    int m0 = blockIdx.y * 4;
    float acc[4];
    float bv = bias[n];
    #pragma unroll
    for (int i = 0; i < 4; i++) acc[i] = bv;
    for (int k = 0; k < Ez; k++) {
        float wv = w[k * 512 + n];
        #pragma unroll
        for (int i = 0; i < 4; i++) acc[i] += h2[(m0 + i) * Ez + k] * wv;
    }
    #pragma unroll
    for (int i = 0; i < 4; i++) hstack[(m0 + i) * Hz + Sz + n] = acc[i];
    if (blockIdx.x == 0 && threadIdx.x < Sz) {
        #pragma unroll
        for (int i = 0; i < 4; i++)
            hstack[(m0 + i) * Hz + threadIdx.x] = x[(m0 + i) * Sz + threadIdx.x];
    }
}

// Persistent cooperative LSTM: 256 WGs (16 groups x 16 slices), 512 threads (8 waves).
// W_hh slice resident in VGPRs; A (h, bf16) via LDS; h DOUBLE-BUFFERED in global
// (write buf[t&1], read buf[1-(t&1)]) -> no read/write race across slice skew.
// Sync: per-slice monotone flags (release store / acquire poll).
__global__ __launch_bounds__(NTHR, 2) void k_lstm(
        const ushort* __restrict__ wbt, const float* __restrict__ rnn_in,
        const float* __restrict__ deltas, const int* __restrict__ h_lens,
        const float* __restrict__ W_ih, const float* __restrict__ b_lstm,
        ushort* h_global, const int* __restrict__ sortedidx,
        float* __restrict__ last, unsigned int* bar) {
    __shared__ __align__(16) ushort a_lds[RG * KW];   // 16,640 B (aliased as gates fp32[16][136])
    __shared__ float c_lds[RG * JW];                  // 2,176 B
    __shared__ int   rowg[RG];
    __shared__ int   hl_s[RG];

    const int tid = threadIdx.x;
    const int g   = blockIdx.x >> 4;
    const int s   = blockIdx.x & 15;

    if (tid < RG) {
        int o = sortedidx[g * RG + tid];
        rowg[tid] = o;
        hl_s[tid] = h_lens[o];
    }
    for (int idx = tid; idx < RG * JW; idx += NTHR) c_lds[idx] = 0.0f;
    __syncthreads();

    const int lane = tid & 63, wvi = tid >> 6;       // wvi 0..7
    const int l15 = lane & 15, quad = lane >> 4;
    const int ntile = (wvi == 0) ? 2 : 1;
    const int tiles[2] = { wvi, 8 };                  // wave 0 also covers tile 8

    int myrows[4];
    #pragma unroll
    for (int r = 0; r < 4; r++) myrows[r] = rowg[quad * 4 + r];
    const int gmax = hl_s[0];

    // ---- B fragments (W_hh slice) persistent in VGPRs: <=2 tiles x 17 x uint4 ----
    s16x8 bfrag[2][KIT];
    #pragma unroll
    for (int i = 0; i < 2; i++) {
        int nl = tiles[i] * 16 + l15;
        bool okrow = (i < ntile) && (nl < NW);
        const uint* wrow = (const uint*)wbt + (size_t)(s * NW + (nl < NW ? nl : 0)) * KD;
        #pragma unroll
        for (int kit = 0; kit < KIT; kit++) {
            s16x8 z = {0, 0, 0, 0, 0, 0, 0, 0};
            if (okrow && (kit * 32 + quad * 8 < KW))
                z = __builtin_bit_cast(s16x8, *(const uint4*)(wrow + kit * 16 + quad * 4));
            bfrag[i][kit] = z;
        }
    }

    // W_ih / bias columns for this lane's n positions
    float wihreg[2][CD1], breg[2];
    #pragma unroll
    for (int i = 0; i < 2; i++) {
        int nl = tiles[i] * 16 + l15;
        int jg = s * JW + (nl >> 2);
        bool ok = (i < ntile) && (nl < NW) && (jg < Hz);
        int col = (nl & 3) * Hz + (jg < Hz ? jg : 0);
        breg[i] = ok ? b_lstm[col] : 0.0f;
        #pragma unroll
        for (int q = 0; q < CD1; q++) wihreg[i][q] = ok ? W_ih[q * H4 + col] : 0.0f;
    }

    // double-buffered h state: buffer b at h_global + b*Bz*KW (ushorts)
    ushort* hbuf0 = h_global + (size_t)g * RG * KW;
    ushort* hbuf1 = h_global + (size_t)Bz * KW + (size_t)g * RG * KW;
    unsigned int* flg = bar + (size_t)(g * NSL) * BARSTRIDE;   // 16 flags, 128B apart

    for (int t = 0; t < gmax; t++) {
        ushort* hw16 = (t & 1) ? hbuf1 : hbuf0;          // write h(t)
        const ushort* hr16 = (t & 1) ? hbuf0 : hbuf1;    // read  h(t-1)  (t=0 -> buf1 = h0)
        const uint* hr32 = (const uint*)hr16;

        // acc init = u_t @ W_ih + b — independent of h(t-1), issued before the wait
        float uu[4][CD1];
        #pragma unroll
        for (int r = 0; r < 4; r++) {
            const float* up = rnn_in + ((size_t)myrows[r] * Tz + t) * CD1;
            #pragma unroll
            for (int q = 0; q < CD1; q++) uu[r][q] = up[q];
        }
        f32x4 acc[2];
        #pragma unroll
        for (int i = 0; i < 2; i++) {
            #pragma unroll
            for (int r = 0; r < 4; r++) {
                float a0 = breg[i];
                #pragma unroll
                for (int q = 0; q < CD1; q++) a0 += uu[r][q] * wihreg[i][q];
                acc[i][r] = a0;
            }
        }

        if (t > 0) {   // wait until all 16 slices have published h(t-1): flag[s'] >= t
            int ready;
            do {
                int ok = 1;
                if (tid < NSL)
                    ok = (__hip_atomic_load(flg + tid * BARSTRIDE, __ATOMIC_ACQUIRE,
                                            __HIP_MEMORY_SCOPE_AGENT) >= (unsigned)t);
                ready = __syncthreads_and(ok);
                if (!ready) __builtin_amdgcn_s_sleep(2);
            } while (!ready);
        }

        // read group h(t-1) (packed bf16 pairs) — relaxed atomics pipeline
        uint hpk[9];
        #pragma unroll
        for (int it = 0; it < 9; it++) {
            int idx = tid + it * NTHR;
            hpk[it] = (idx < HGD)
                ? __hip_atomic_load(hr32 + idx, __ATOMIC_RELAXED, __HIP_MEMORY_SCOPE_AGENT)
                : 0u;
        }
        #pragma unroll
        for (int it = 0; it < 9; it++) {
            int idx = tid + it * NTHR;
            if (idx < HGD) ((uint*)a_lds)[idx] = hpk[it];
        }
        __syncthreads();

        // MFMA k-loop: A from LDS, B from registers
        for (int kit = 0; kit < KIT; kit++) {
            int kq = kit * 32 + quad * 8;
            s16x8 af = {0, 0, 0, 0, 0, 0, 0, 0};
            if (kq < KW)
                af = __builtin_bit_cast(s16x8,
                    *(const uint4*)((const uint*)a_lds + l15 * KD + kit * 16 + quad * 4));
            #pragma unroll
            for (int i = 0; i < 2; i++) {
                if (i >= ntile) break;
                acc[i] = __builtin_amdgcn_mfma_f32_16x16x32_bf16(af, bfrag[i][kit], acc[i], 0, 0, 0);
            }
        }
        __syncthreads();   // a_lds reads done; safe to alias as gates

        // gates (pre-activation) -> LDS, aliasing a_lds
        float* gates = (float*)a_lds;
        #pragma unroll
        for (int i = 0; i < 2; i++) {
            if (i >= ntile) break;
            int nl = tiles[i] * 16 + l15;
            if (nl < NW) {
                #pragma unroll
                for (int r = 0; r < 4; r++) gates[(quad * 4 + r) * NW + nl] = acc[i][r];
            }
        }
        __syncthreads();

        // elementwise cell update; h(t) -> write buffer; capture 'last' at t == hl-1
        for (int p = tid; p < RG * JW; p += NTHR) {
            int m = p / JW, jj = p - m * JW;
            int jglob = s * JW + jj;
            if (jglob < Hz && t < hl_s[m]) {
                float4 gv = *(const float4*)(gates + m * NW + jj * 4);
                float ig = sigf(gv.x), fg = sigf(gv.y), gt = tanhf(gv.z), og = sigf(gv.w);
                float cp = c_lds[p];
                float cn = fg * cp + ig * gt;
                float hn = og * tanhf(cn);
                c_lds[p] = cn;
                int hidx = m * KW + jglob;
                if (t == hl_s[m] - 1) {
                    ushort hpv = __hip_atomic_load((const ushort*)hr16 + hidx,
                                                   __ATOMIC_RELAXED, __HIP_MEMORY_SCOPE_AGENT);
                    float hp = bf2f(hpv);
                    int orig = rowg[m];
                    float d = deltas[(size_t)orig * Tz + t];
                    last[(size_t)orig * Hz + jglob] = (1.0f - d) * hp + d * hn;
                }
                __hip_atomic_store(hw16 + hidx, f2bf(hn),
                                   __ATOMIC_RELAXED, __HIP_MEMORY_SCOPE_AGENT);
            }
        }

        // publish h(t): syncthreads drains all waves' stores, then release flag
        __syncthreads();
        if (tid == 0)
            __hip_atomic_store(flg + s * BARSTRIDE, (unsigned)(t + 1),
                               __ATOMIC_RELEASE, __HIP_MEMORY_SCOPE_AGENT);
    }
}

// final projection: (256,1040) @ (1040,8) + bias, one block per row
__global__ void k_dec3(const float* __restrict__ z2, const float* __restrict__ w,
                       const float* __restrict__ bias, float* __restrict__ out) {
    int m = blockIdx.x, tid = threadIdx.x;
    float p[8];
    #pragma unroll
    for (int n = 0; n < 8; n++) p[n] = 0.0f;
    for (int k = tid; k < Dz; k += 256) {
        float zv = z2[(size_t)m * Dz + k];
        #pragma unroll
        for (int n = 0; n < 8; n++) p[n] += zv * w[k * 8 + n];
    }
    __shared__ float red[256][8];
    #pragma unroll
    for (int n = 0; n < 8; n++) red[tid][n] = p[n];
    __syncthreads();
    for (int s2 = 128; s2 > 0; s2 >>= 1) {
        if (tid < s2) {
            #pragma unroll
            for (int n = 0; n < 8; n++) red[tid][n] += red[tid + s2][n];
        }
        __syncthreads();
    }
    if (tid < 8) out[m * 8 + tid] = red[0][tid] + bias[tid];
}

extern "C" void kernel_launch(void* const* d_in, const int* in_sizes, int n_in,
                              void* d_out, int out_size, void* d_ws, size_t ws_size,
                              hipStream_t stream) {
    const float* x       = (const float*)d_in[0];
    const float* rnn_inp = (const float*)d_in[1];
    const float* deltas  = (const float*)d_in[2];
    const int*   h_lens  = (const int*)  d_in[3];
    const float* enc_w1  = (const float*)d_in[4];
    const float* enc_b1  = (const float*)d_in[5];
    const float* enc_w2  = (const float*)d_in[6];
    const float* enc_b2  = (const float*)d_in[7];
    const float* enc_w3  = (const float*)d_in[8];
    const float* enc_b3  = (const float*)d_in[9];
    const float* W_ih    = (const float*)d_in[10];
    const float* W_hh    = (const float*)d_in[11];
    const float* b_lstm  = (const float*)d_in[12];
    const float* dec_w1  = (const float*)d_in[13];
    const float* dec_b1  = (const float*)d_in[14];
    const float* dec_w2  = (const float*)d_in[15];
    const float* dec_b2  = (const float*)d_in[16];
    const float* dec_w3  = (const float*)d_in[17];
    const float* dec_b3  = (const float*)d_in[18];
    (void)in_sizes; (void)n_in; (void)out_size; (void)ws_size;

    char* base = (char*)d_ws;
    size_t off = 0;
    auto alloc = [&](size_t bytes) { void* p = base + off; off = (off + bytes + 255) & ~(size_t)255; return p; };
    ushort* wbt      = (ushort*)alloc((size_t)NW * NSL * KW * 2);   // 2,263,040
    ushort* h_glob   = (ushort*)alloc((size_t)2 * Bz * KW * 2);     // 532,480 (2 buffers)
    float*  hA       = (float*) alloc((size_t)Bz * KW * 4);
    float*  h1       = (float*) alloc((size_t)Bz * Ez * 4);
    float*  h2       = (float*) alloc((size_t)Bz * Ez * 4);
    float*  lastb    = (float*) alloc((size_t)Bz * Hz * 4);
    float*  z1       = (float*) alloc((size_t)Bz * Dz * 4);
    float*  z2       = (float*) alloc((size_t)Bz * Dz * 4);
    int*    sortedix = (int*)   alloc(Bz * 4);
    unsigned int* bar = (unsigned int*)alloc((size_t)NG * NSL * BARSTRIDE * 4);
    float*  outp = (float*)d_out;

    hipMemsetAsync(bar, 0, (size_t)NG * NSL * BARSTRIDE * 4, stream);
    k_sort<<<1, 256, 0, stream>>>(h_lens, sortedix);
    {
        int total = NW * NSL * KW;
        k_prep_w<<<(total + 255) / 256, 256, 0, stream>>>(W_hh, wbt);
    }

    k_mlp<Sz, Ez, 1><<<dim3(4, 64), 256, 0, stream>>>(x,  enc_w1, enc_b1, h1);
    k_mlp<Ez, Ez, 1><<<dim3(4, 64), 256, 0, stream>>>(h1, enc_w2, enc_b2, h2);
    k_enc3<<<dim3(2, 64), 256, 0, stream>>>(h2, enc_w3, enc_b3, x, hA);
    {
        int total = Bz * KW / 2;
        // seed buffer 1 (read at t=0)
        k_hinit<<<(total + 255) / 256, 256, 0, stream>>>(hA, sortedix,
                                                         (uint*)(h_glob + (size_t)Bz * KW));
    }

    {
        void* args[] = { (void*)&wbt, (void*)&rnn_inp, (void*)&deltas, (void*)&h_lens,
                         (void*)&W_ih, (void*)&b_lstm, (void*)&h_glob, (void*)&sortedix,
                         (void*)&lastb, (void*)&bar };
        hipLaunchCooperativeKernel(reinterpret_cast<void*>(k_lstm), dim3(NG * NSL), dim3(NTHR),
                                   args, 0, stream);
    }

    k_mlp<Hz, Dz, 1><<<dim3(5, 64), 256, 0, stream>>>(lastb, dec_w1, dec_b1, z1);
    k_mlp<Dz, Dz, 1><<<dim3(5, 64), 256, 0, stream>>>(z1,   dec_w2, dec_b2, z2);
    k_dec3<<<Bz, 256, 0, stream>>>(z2, dec_w3, dec_b3, outp);
}